// Round 10
// baseline (238.203 us; speedup 1.0000x reference)
//
#include <hip/hip_runtime.h>
#include <hip/hip_bf16.h>

// Inputs/outputs are f32 (proven: round-5 bf16 -> NaN; rounds 4/6 passed on f32 path).

// problem constants (fixed by harness shapes)
#define NS   4
#define NPX  4096
#define NSZ  24
#define PS   64
#define VINW 520   // 3 blended + 256 ictx + 256 pf + 5 pad
#define CW   66    // LDS row width: 64 cols + 2-col zero halo

// out element offsets
#define OFF0 0        // ref_novel_view (3,4096)
#define OFF1 12288    // blended_img    (3,4096)
#define OFF2 24576    // interp_view    (4,3,4096)
#define OFF3 73728    // weight         (4,4096,24)
#define OFF4 466944   // confs          (4,4096)

// ---------------------------------------------------------------------------
// Static device-global scratch. ce/ctx stored as SEPARATE bf16 arrays (1 MB
// per source total) so the k_epi gather working set fits per-XCD L2 once the
// XCD swizzle pins each source to one XCD pair.
// ---------------------------------------------------------------------------
__device__ unsigned short g_ce2 [NS * NPX * 64];   // bf16 [s][p][ch]
__device__ unsigned short g_ct2 [NS * NPX * 64];   // bf16 [s][p][ch]
__device__ unsigned short g_vin [NPX * VINW];      // bf16 [p][ch: 0-2 bl, 3-258 ictx, 259-514 pf]
__device__ float g_iv  [NS * NPX * 3];    // [s][p][c]
__device__ float g_clg [NS * NPX];        // confNet logit per (source,pixel)
__device__ float g_bl  [3 * NPX];         // blended, channel-plane (f32)
// transposed weights (lane-coalesced on the fast index)
__device__ float g_fwT [162 * 64];        // [(ic*9+t)][oc]
__device__ float g_cwT [27 * 64];         // [(ic*9+t)][oc]
__device__ float g_pwT [54 * 64];         // [(ic*9+t)][oc]
__device__ unsigned short g_vwT [3 * 9 * 515];  // bf16 [(oc*9+t)][ch] — 27 KB, L1-resident

__device__ __forceinline__ int clampi(int v, int lo, int hi) {
    return v < lo ? lo : (v > hi ? hi : v);
}
__device__ __forceinline__ unsigned bf16_bits(float f) {   // RNE f32->bf16 bits
    unsigned u = __float_as_uint(f);
    return (u + 0x7fffu + ((u >> 16) & 1u)) >> 16;
}
__device__ __forceinline__ float ldbf(const unsigned short* p, int i) {
    return __uint_as_float(((unsigned)p[i]) << 16);
}

// ---------------------------------------------------------------------------
// Kernel 0: weight transposes (same work every call).
// ---------------------------------------------------------------------------
__global__ void k_prep(const float* __restrict__ fw, const float* __restrict__ cw,
                       const float* __restrict__ pw, const float* __restrict__ vw)
{
    const int i = blockIdx.x * 256 + threadIdx.x;
    const int stride = gridDim.x * 256;
    for (int d = i; d < 162 * 64; d += stride) g_fwT[d] = fw[(d & 63) * 162 + (d >> 6)];
    for (int d = i; d < 27 * 64;  d += stride) g_cwT[d] = cw[(d & 63) * 27  + (d >> 6)];
    for (int d = i; d < 54 * 64;  d += stride) g_pwT[d] = pw[(d & 63) * 54  + (d >> 6)];
    for (int d = i; d < 13905;    d += stride) {
        int oc = d / 4635, rem = d % 4635, t = rem / 515, ch = rem % 515;
        g_vwT[d] = (unsigned short)bf16_bits(vw[(oc * 515 + ch) * 9 + t]);
    }
}

// ---------------------------------------------------------------------------
// Kernel 1: flowRefNet + ctxNet convs, ROW-TILED.
// block = (s, py): 256 threads = 4 waves; wave w -> px in [16w,16w+16), lane = oc.
// ---------------------------------------------------------------------------
__global__ __launch_bounds__(256) void k_convs(
    const float* __restrict__ sv, const float* __restrict__ sf, const float* __restrict__ wv,
    const float* __restrict__ flow_b, const float* __restrict__ ctx_b)
{
    __shared__ float lds[18 * 3 * CW];
    const int s  = blockIdx.x >> 6, py = blockIdx.x & 63;
    const int tid = threadIdx.x;

    for (int i = tid; i < 18 * 3 * CW; i += 256) lds[i] = 0.f;
    __syncthreads();
    for (int i = tid; i < 18 * 3 * 64; i += 256) {
        const int col = i & 63;
        const int r   = (i >> 6) % 3;
        const int pl  = i / 192;
        const int iy  = py + r - 1;
        if ((unsigned)iy < 64u) {
            const float* src = (pl < 6) ? (sf + (s * 6 + pl) * NPX)
                             : (pl < 9) ? (sv + (s * 3 + (pl - 6)) * NPX)
                                        : (wv + (s * 9 + (pl - 9)) * NPX);
            lds[(pl * 3 + r) * CW + col + 1] = src[iy * 64 + col];
        }
    }
    __syncthreads();

    const int oc  = tid & 63;
    const int px0 = (tid >> 6) * 16;

    float acc_ce[16], acc_ctx[16];
    const float fb = flow_b[oc], cb = ctx_b[oc];
    #pragma unroll
    for (int j = 0; j < 16; ++j) { acc_ce[j] = fb; acc_ctx[j] = cb; }

    for (int pl = 0; pl < 18; ++pl) {
        float w[9];
        #pragma unroll
        for (int t = 0; t < 9; ++t) w[t] = g_fwT[(pl * 9 + t) * 64 + oc];
        float wc[9];
        const bool has_ctx = (pl >= 6 && pl < 9);
        if (has_ctx) {
            #pragma unroll
            for (int t = 0; t < 9; ++t) wc[t] = g_cwT[((pl - 6) * 9 + t) * 64 + oc];
        }
        float c0[3], c1[3], c2[3];
        #pragma unroll
        for (int r = 0; r < 3; ++r) {
            c0[r] = lds[(pl * 3 + r) * CW + px0];
            c1[r] = lds[(pl * 3 + r) * CW + px0 + 1];
        }
        #pragma unroll
        for (int j = 0; j < 16; ++j) {
            #pragma unroll
            for (int r = 0; r < 3; ++r)
                c2[r] = lds[(pl * 3 + r) * CW + px0 + j + 2];
            float a = 0.f;
            #pragma unroll
            for (int r = 0; r < 3; ++r)
                a += c0[r] * w[r * 3 + 0] + c1[r] * w[r * 3 + 1] + c2[r] * w[r * 3 + 2];
            acc_ce[j] += a;
            if (has_ctx) {
                float b2 = 0.f;
                #pragma unroll
                for (int r = 0; r < 3; ++r)
                    b2 += c0[r] * wc[r * 3 + 0] + c1[r] * wc[r * 3 + 1] + c2[r] * wc[r * 3 + 2];
                acc_ctx[j] += b2;
            }
            #pragma unroll
            for (int r = 0; r < 3; ++r) { c0[r] = c1[r]; c1[r] = c2[r]; }
        }
    }
    #pragma unroll
    for (int j = 0; j < 16; ++j) {
        const int p = py * 64 + px0 + j;
        g_ce2[(s * NPX + p) * 64 + oc] = (unsigned short)bf16_bits(fmaxf(acc_ce[j], 0.f));
        g_ct2[(s * NPX + p) * 64 + oc] = (unsigned short)bf16_bits(fmaxf(acc_ctx[j], 0.f));
    }
}

// ---------------------------------------------------------------------------
// Kernel 2: epipolar gathers + mu/var + weightNet softmax + interpolations.
// 4096 blocks x 256 threads; wave = one (s,p). XCD swizzle: s = (blk&7)>>1
// (blockIdx%8 ~ XCD round-robin) pins each source's 1 MB ce/ctx + its ang/spa
// slice to one XCD pair -> L2-resident gathers.
// ---------------------------------------------------------------------------
__global__ __launch_bounds__(256) void k_epi(
    const float* __restrict__ sv, const float* __restrict__ sf, const int* __restrict__ nxy,
    const float* __restrict__ spa, const float* __restrict__ ang,
    const float* __restrict__ wnet_w, const float* __restrict__ wnet_b,
    const float* __restrict__ cnet_w,
    float* __restrict__ out)
{
    const int blk = blockIdx.x;
    const int wid = threadIdx.x >> 6;          // wave in block
    const int l   = threadIdx.x & 63;
    const int s   = (blk & 7) >> 1;
    const int p   = (blk >> 3) * 8 + (blk & 1) * 4 + wid;

    int q[NSZ];
    #pragma unroll
    for (int e = 0; e < 8; ++e) {
        int nx = nxy[((s * NPX + p) * 8 + e) * 2 + 0];
        int ny = nxy[((s * NPX + p) * 8 + e) * 2 + 1];
        nx = clampi(nx, 0, 63);
        #pragma unroll
        for (int k = 0; k < 3; ++k) {
            int y = clampi(ny + k - 1, 0, 63);
            q[e * 3 + k] = y * 64 + nx;
        }
    }

    const unsigned short* cep = g_ce2 + (size_t)s * NPX * 64;
    const unsigned short* ctp = g_ct2 + (size_t)s * NPX * 64;

    float ceu[NSZ];
    #pragma unroll
    for (int n = 0; n < NSZ; ++n) ceu[n] = ldbf(cep, q[n] * 64 + l);

    float mu = 0.f;
    #pragma unroll
    for (int n = 0; n < NSZ; ++n) mu += ceu[n];
    mu *= (1.f / 24.f);

    const float Wce  = wnet_w[6 + l];
    const float Cce  = cnet_w[6 + l];
    float var = 0.f;
    float wpart[NSZ], cpart[NSZ];
    #pragma unroll
    for (int n = 0; n < NSZ; ++n) {
        const float d = ceu[n] - mu;
        var += d * d;
        wpart[n] = ceu[n] * Wce;
        cpart[n] = ceu[n] * Cce;
    }
    var *= (1.f / 23.f);   // ddof=1

    const float base_w = mu * wnet_w[70 + l] + var * wnet_w[134 + l];
    const float base_c = mu * cnet_w[70 + l] + var * cnet_w[134 + l];
    const int   ech = (l < 6) ? l : clampi(192 + l, 198, 205);
    const float We  = (l < 14) ? wnet_w[ech] : 0.f;
    const float Ce  = (l < 14) ? cnet_w[ech] : 0.f;

    if (l < 14) {
        #pragma unroll
        for (int n = 0; n < NSZ; ++n) {
            float ev;
            if (l < 6)      ev = sf[(s * 6 + l) * NPX + q[n]];
            else if (l < 8) ev = spa[((s * 2 + (l - 6)) * NSZ + n) * NPX + p];
            else            ev = ang[((s * 6 + (l - 8)) * NSZ + n) * NPX + p];
            wpart[n] += ev * We + base_w;
            cpart[n] += ev * Ce + base_c;
        }
    } else {
        #pragma unroll
        for (int n = 0; n < NSZ; ++n) { wpart[n] += base_w; cpart[n] += base_c; }
    }

    // butterfly reduce the 24 weight-logits only
    #pragma unroll
    for (int off = 32; off; off >>= 1) {
        #pragma unroll
        for (int n = 0; n < NSZ; ++n)
            wpart[n] += __shfl_xor(wpart[n], off, 64);
    }

    // softmax over nsz (weightNet)
    const float wb = wnet_b[0];
    float m = wpart[0] + wb;
    #pragma unroll
    for (int n = 0; n < NSZ; ++n) { wpart[n] += wb; m = fmaxf(m, wpart[n]); }
    float ssum = 0.f;
    #pragma unroll
    for (int n = 0; n < NSZ; ++n) { wpart[n] = __expf(wpart[n] - m); ssum += wpart[n]; }
    const float inv = 1.f / ssum;
    #pragma unroll
    for (int n = 0; n < NSZ; ++n) wpart[n] *= inv;   // wpart now = wgt (all lanes)

    // confNet logit: per-lane channel contribution, single scalar butterfly
    float cl = 0.f;
    #pragma unroll
    for (int n = 0; n < NSZ; ++n) cl += cpart[n] * wpart[n];
    #pragma unroll
    for (int off = 32; off; off >>= 1) cl += __shfl_xor(cl, off, 64);
    if (l == 0) g_clg[s * NPX + p] = cl;

    // out3: weight [s][p][n] — distributed store, lanes 0..23
    float wsel = wpart[0];
    #pragma unroll
    for (int n = 1; n < NSZ; ++n) wsel = (l == n) ? wpart[n] : wsel;
    if (l < NSZ) out[OFF3 + (s * NPX + p) * NSZ + l] = wsel;

    // interp_ctx channel l
    float sc = 0.f;
    #pragma unroll
    for (int n = 0; n < NSZ; ++n) sc += ldbf(ctp, q[n] * 64 + l) * wpart[n];
    g_vin[p * VINW + 3 + s * 64 + l] = (unsigned short)bf16_bits(sc);

    // interp_view (lanes 0..2)
    if (l < 3) {
        float svv = 0.f;
        #pragma unroll
        for (int n = 0; n < NSZ; ++n) svv += sv[(s * 3 + l) * NPX + q[n]] * wpart[n];
        g_iv[(s * NPX + p) * 3 + l] = svv;
        out[OFF2 + (s * 3 + l) * NPX + p] = svv;
    }
}

// ---------------------------------------------------------------------------
// Kernel 3: confNet softmax over sources + blended image. 1 thread / pixel.
// ---------------------------------------------------------------------------
__global__ __launch_bounds__(64) void k_conf(
    const float* __restrict__ cnet_b, float* __restrict__ out)
{
    const int p = blockIdx.x * 64 + threadIdx.x;
    const float cb = cnet_b[0];

    float lg[NS];
    #pragma unroll
    for (int s = 0; s < NS; ++s) lg[s] = g_clg[s * NPX + p] + cb;
    float m = lg[0];
    #pragma unroll
    for (int s = 1; s < NS; ++s) m = fmaxf(m, lg[s]);
    float ssum = 0.f;
    float conf[NS];
    #pragma unroll
    for (int s = 0; s < NS; ++s) { conf[s] = __expf(lg[s] - m); ssum += conf[s]; }
    const float inv = 1.f / ssum;
    #pragma unroll
    for (int s = 0; s < NS; ++s) {
        conf[s] *= inv;
        out[OFF4 + s * NPX + p] = conf[s];
    }
    #pragma unroll
    for (int c = 0; c < 3; ++c) {
        float acc = 0.f;
        #pragma unroll
        for (int s = 0; s < NS; ++s)
            acc += g_iv[(s * NPX + p) * 3 + c] * conf[s];
        g_bl[c * NPX + p] = acc;
        g_vin[p * VINW + c] = (unsigned short)bf16_bits(acc);
        out[OFF1 + c * NPX + p] = acc;
    }
}

// ---------------------------------------------------------------------------
// Kernel 4: psvNet, ROW-TILED. block = (s, py): 256 threads = 4 waves,
// wave -> 16 px, lane = oc. Planes 0..23 = psv (ic*8+d), 24..26 = blended ic.
// ---------------------------------------------------------------------------
__global__ __launch_bounds__(256) void k_psv(
    const float* __restrict__ psvs, const float* __restrict__ psv_b)
{
    __shared__ float lds[27 * 3 * CW];
    const int s  = blockIdx.x >> 6, py = blockIdx.x & 63;
    const int tid = threadIdx.x;

    for (int i = tid; i < 27 * 3 * CW; i += 256) lds[i] = 0.f;
    __syncthreads();
    for (int i = tid; i < 27 * 3 * 64; i += 256) {
        const int col = i & 63;
        const int r   = (i >> 6) % 3;
        const int pl  = i / 192;
        const int iy  = py + r - 1;
        if ((unsigned)iy < 64u) {
            const float* src = (pl < 24) ? (psvs + (s * 24 + pl) * NPX)
                                         : (g_bl + (pl - 24) * NPX);
            lds[(pl * 3 + r) * CW + col + 1] = src[iy * 64 + col];
        }
    }
    __syncthreads();

    const int oc  = tid & 63;
    const int px0 = (tid >> 6) * 16;
    const float bias = psv_b[oc];

    float wp[3][9];
    #pragma unroll
    for (int ic = 0; ic < 3; ++ic)
        #pragma unroll
        for (int t = 0; t < 9; ++t) wp[ic][t] = g_pwT[(ic * 9 + t) * 64 + oc];

    float bconst[16];
    #pragma unroll
    for (int j = 0; j < 16; ++j) bconst[j] = bias;
    for (int ic = 0; ic < 3; ++ic) {
        float w[9];
        #pragma unroll
        for (int t = 0; t < 9; ++t) w[t] = g_pwT[((3 + ic) * 9 + t) * 64 + oc];
        const int pl = 24 + ic;
        float c0[3], c1[3], c2[3];
        #pragma unroll
        for (int r = 0; r < 3; ++r) {
            c0[r] = lds[(pl * 3 + r) * CW + px0];
            c1[r] = lds[(pl * 3 + r) * CW + px0 + 1];
        }
        #pragma unroll
        for (int j = 0; j < 16; ++j) {
            #pragma unroll
            for (int r = 0; r < 3; ++r)
                c2[r] = lds[(pl * 3 + r) * CW + px0 + j + 2];
            float a = 0.f;
            #pragma unroll
            for (int r = 0; r < 3; ++r)
                a += c0[r] * w[r * 3 + 0] + c1[r] * w[r * 3 + 1] + c2[r] * w[r * 3 + 2];
            bconst[j] += a;
            #pragma unroll
            for (int r = 0; r < 3; ++r) { c0[r] = c1[r]; c1[r] = c2[r]; }
        }
    }

    float acc[16];
    #pragma unroll
    for (int j = 0; j < 16; ++j) acc[j] = 0.f;

    for (int d = 0; d < 8; ++d) {
        float a[16];
        #pragma unroll
        for (int j = 0; j < 16; ++j) a[j] = bconst[j];
        #pragma unroll
        for (int ic = 0; ic < 3; ++ic) {
            const int pl = ic * 8 + d;
            float c0[3], c1[3], c2[3];
            #pragma unroll
            for (int r = 0; r < 3; ++r) {
                c0[r] = lds[(pl * 3 + r) * CW + px0];
                c1[r] = lds[(pl * 3 + r) * CW + px0 + 1];
            }
            #pragma unroll
            for (int j = 0; j < 16; ++j) {
                #pragma unroll
                for (int r = 0; r < 3; ++r)
                    c2[r] = lds[(pl * 3 + r) * CW + px0 + j + 2];
                float t2 = 0.f;
                #pragma unroll
                for (int r = 0; r < 3; ++r)
                    t2 += c0[r] * wp[ic][r * 3 + 0] + c1[r] * wp[ic][r * 3 + 1] + c2[r] * wp[ic][r * 3 + 2];
                a[j] += t2;
                #pragma unroll
                for (int r = 0; r < 3; ++r) { c0[r] = c1[r]; c1[r] = c2[r]; }
            }
        }
        #pragma unroll
        for (int j = 0; j < 16; ++j) acc[j] += fmaxf(a[j], 0.f);
    }
    #pragma unroll
    for (int j = 0; j < 16; ++j)
        g_vin[(py * 64 + px0 + j) * VINW + 259 + s * 64 + oc] =
            (unsigned short)bf16_bits(acc[j] * 0.125f);
}

// ---------------------------------------------------------------------------
// Kernel 5: vref conv3x3 over 515 channels (g_vin, bf16) -> 3. grid 4096, block 64.
// ---------------------------------------------------------------------------
__global__ __launch_bounds__(64) void k_vref(
    const float* __restrict__ vref_b, float* __restrict__ out)
{
    const int p = blockIdx.x;
    const int py = p >> 6, px = p & 63;
    const int l = threadIdx.x;

    float acc[3] = {0.f, 0.f, 0.f};
    #pragma unroll
    for (int k = 0; k < 9; ++k) {
        const int ch = k * 64 + l;
        if (ch >= 515) break;
        #pragma unroll
        for (int t = 0; t < 9; ++t) {
            const int iy = py + t / 3 - 1, ix = px + t % 3 - 1;
            if ((unsigned)iy >= 64u || (unsigned)ix >= 64u) continue;
            const float v = ldbf(g_vin, (iy * 64 + ix) * VINW + ch);
            #pragma unroll
            for (int oc = 0; oc < 3; ++oc)
                acc[oc] += v * ldbf(g_vwT, (oc * 9 + t) * 515 + ch);
        }
    }
    #pragma unroll
    for (int off = 32; off; off >>= 1) {
        #pragma unroll
        for (int oc = 0; oc < 3; ++oc)
            acc[oc] += __shfl_xor(acc[oc], off, 64);
    }
    if (l == 0) {
        #pragma unroll
        for (int oc = 0; oc < 3; ++oc)
            out[OFF0 + oc * NPX + p] = acc[oc] + vref_b[oc];
    }
}

// ---------------------------------------------------------------------------
extern "C" void kernel_launch(void* const* d_in, const int* in_sizes, int n_in,
                              void* d_out, int out_size, void* d_ws, size_t ws_size,
                              hipStream_t stream)
{
    auto find1 = [&](int sz, int fb) -> int {
        for (int i = 0; i < n_in; ++i) if (in_sizes[i] == sz) return i;
        return fb;
    };
    const int i_sv  = find1(49152, 0);
    const int i_sf  = find1(98304, 1);
    const int i_psv = find1(393216, 2);
    const int i_wv  = find1(147456, 3);
    const int i_nxy = find1(262144, 5);
    const int i_spa = find1(786432, 6);
    const int i_ang = find1(2359296, 7);
    const int i_fw  = find1(10368, 9);
    const int i_cw  = find1(1728, 11);
    const int i_pw  = find1(3456, 17);
    const int i_vw  = find1(13905, 19);
    const int i_vb  = find1(3, 20);
    int i_ww = -1, i_cnw = -1;
    for (int i = 0; i < n_in; ++i)
        if (in_sizes[i] == 206) { if (i_ww < 0) i_ww = i; else { i_cnw = i; break; } }
    if (i_ww  < 0) i_ww  = 13;
    if (i_cnw < 0) i_cnw = 15;
    int b64[3] = {10, 12, 18}; int c64 = 0;
    for (int i = 0; i < n_in && c64 < 3; ++i) if (in_sizes[i] == 64) b64[c64++] = i;
    const int i_fb = b64[0], i_cb = b64[1], i_pb = b64[2];
    int i_wb = -1, i_cnb = -1;
    for (int i = i_fw + 1; i < n_in; ++i)
        if (in_sizes[i] == 1) { if (i_wb < 0) i_wb = i; else { i_cnb = i; break; } }
    if (i_wb  < 0) i_wb  = 14;
    if (i_cnb < 0) i_cnb = 16;

    const float* sv     = (const float*)d_in[i_sv];
    const float* sf     = (const float*)d_in[i_sf];
    const float* psvs   = (const float*)d_in[i_psv];
    const float* wv     = (const float*)d_in[i_wv];
    const int*   nxy    = (const int*)d_in[i_nxy];
    const float* spa    = (const float*)d_in[i_spa];
    const float* ang    = (const float*)d_in[i_ang];
    const float* flow_w = (const float*)d_in[i_fw];
    const float* flow_b = (const float*)d_in[i_fb];
    const float* ctx_w  = (const float*)d_in[i_cw];
    const float* ctx_b  = (const float*)d_in[i_cb];
    const float* wnet_w = (const float*)d_in[i_ww];
    const float* wnet_b = (const float*)d_in[i_wb];
    const float* cnet_w = (const float*)d_in[i_cnw];
    const float* cnet_b = (const float*)d_in[i_cnb];
    const float* psv_w  = (const float*)d_in[i_pw];
    const float* psv_b  = (const float*)d_in[i_pb];
    const float* vref_w = (const float*)d_in[i_vw];
    const float* vref_b = (const float*)d_in[i_vb];
    (void)d_ws; (void)ws_size; (void)out_size;

    float* out = (float*)d_out;

    k_prep <<<64, 256, 0, stream>>>(flow_w, ctx_w, psv_w, vref_w);
    k_convs<<<256, 256, 0, stream>>>(sv, sf, wv, flow_b, ctx_b);
    k_epi  <<<4096, 256, 0, stream>>>(sv, sf, nxy, spa, ang, wnet_w, wnet_b, cnet_w, out);
    k_conf <<<64, 64, 0, stream>>>(cnet_b, out);
    k_psv  <<<256, 256, 0, stream>>>(psvs, psv_b);
    k_vref <<<4096, 64, 0, stream>>>(vref_b, out);
}

// Round 11
// 220.347 us; speedup vs baseline: 1.0810x; 1.0810x over previous
//
#include <hip/hip_runtime.h>
#include <hip/hip_bf16.h>

// Inputs/outputs are f32 (proven: round-5 bf16 -> NaN; rounds 4/6 passed on f32 path).

// problem constants (fixed by harness shapes)
#define NS   4
#define NPX  4096
#define NSZ  24
#define PS   64
#define VINW 520   // 3 blended + 256 ictx + 256 pf + 5 pad
#define CW   66    // LDS row width: 64 cols + 2-col zero halo

// out element offsets
#define OFF0 0        // ref_novel_view (3,4096)
#define OFF1 12288    // blended_img    (3,4096)
#define OFF2 24576    // interp_view    (4,3,4096)
#define OFF3 73728    // weight         (4,4096,24)
#define OFF4 466944   // confs          (4,4096)

// ---------------------------------------------------------------------------
// Static device-global scratch.
// g_fld[s][p] = (Aw, Ac): per-pixel score fields = Σ_ch ce·W[ce-ch] + Σ_c sf·W[sf-ch]
// for weightNet / confNet — linearizes the gather-side channel reduction.
// ---------------------------------------------------------------------------
__device__ float2 g_fld[NS * NPX];
__device__ unsigned short g_ce2 [NS * NPX * 64];   // bf16 [s][p][ch]
__device__ unsigned short g_ct2 [NS * NPX * 64];   // bf16 [s][p][ch]
__device__ unsigned short g_vin [NPX * VINW];      // bf16 [p][ch]
__device__ float g_iv  [NS * NPX * 3];    // [s][p][c]
__device__ float g_clg [NS * NPX];        // confNet logit per (source,pixel)
__device__ float g_bl  [3 * NPX];         // blended, channel-plane (f32)
// transposed weights (lane-coalesced on the fast index)
__device__ float g_fwT [162 * 64];        // [(ic*9+t)][oc]
__device__ float g_cwT [27 * 64];         // [(ic*9+t)][oc]
__device__ float g_pwT [54 * 64];         // [(ic*9+t)][oc]
__device__ unsigned short g_vwT [3 * 9 * 515];  // bf16 [(oc*9+t)][ch]

__device__ __forceinline__ int clampi(int v, int lo, int hi) {
    return v < lo ? lo : (v > hi ? hi : v);
}
__device__ __forceinline__ unsigned bf16_bits(float f) {   // RNE f32->bf16 bits
    unsigned u = __float_as_uint(f);
    return (u + 0x7fffu + ((u >> 16) & 1u)) >> 16;
}
__device__ __forceinline__ float ldbf(const unsigned short* p, int i) {
    return __uint_as_float(((unsigned)p[i]) << 16);
}

// ---------------------------------------------------------------------------
// Kernel 0: weight transposes (same work every call).
// ---------------------------------------------------------------------------
__global__ void k_prep(const float* __restrict__ fw, const float* __restrict__ cw,
                       const float* __restrict__ pw, const float* __restrict__ vw)
{
    const int i = blockIdx.x * 256 + threadIdx.x;
    const int stride = gridDim.x * 256;
    for (int d = i; d < 162 * 64; d += stride) g_fwT[d] = fw[(d & 63) * 162 + (d >> 6)];
    for (int d = i; d < 27 * 64;  d += stride) g_cwT[d] = cw[(d & 63) * 27  + (d >> 6)];
    for (int d = i; d < 54 * 64;  d += stride) g_pwT[d] = pw[(d & 63) * 54  + (d >> 6)];
    for (int d = i; d < 13905;    d += stride) {
        int oc = d / 4635, rem = d % 4635, t = rem / 515, ch = rem % 515;
        g_vwT[d] = (unsigned short)bf16_bits(vw[(oc * 515 + ch) * 9 + t]);
    }
}

// ---------------------------------------------------------------------------
// Kernel 1: flowRefNet + ctxNet convs, ROW-TILED, + per-pixel score fields.
// block = (s, py): 256 threads = 4 waves; wave w -> px in [16w,16w+16), lane = oc.
// ---------------------------------------------------------------------------
__global__ __launch_bounds__(256) void k_convs(
    const float* __restrict__ sv, const float* __restrict__ sf, const float* __restrict__ wv,
    const float* __restrict__ flow_b, const float* __restrict__ ctx_b,
    const float* __restrict__ wnet_w, const float* __restrict__ cnet_w)
{
    __shared__ float lds[18 * 3 * CW];
    const int s  = blockIdx.x >> 6, py = blockIdx.x & 63;
    const int tid = threadIdx.x;

    for (int i = tid; i < 18 * 3 * CW; i += 256) lds[i] = 0.f;
    __syncthreads();
    for (int i = tid; i < 18 * 3 * 64; i += 256) {
        const int col = i & 63;
        const int r   = (i >> 6) % 3;
        const int pl  = i / 192;
        const int iy  = py + r - 1;
        if ((unsigned)iy < 64u) {
            const float* src = (pl < 6) ? (sf + (s * 6 + pl) * NPX)
                             : (pl < 9) ? (sv + (s * 3 + (pl - 6)) * NPX)
                                        : (wv + (s * 9 + (pl - 9)) * NPX);
            lds[(pl * 3 + r) * CW + col + 1] = src[iy * 64 + col];
        }
    }
    __syncthreads();

    const int oc  = tid & 63;
    const int px0 = (tid >> 6) * 16;

    float acc_ce[16], acc_ctx[16];
    const float fb = flow_b[oc], cb = ctx_b[oc];
    #pragma unroll
    for (int j = 0; j < 16; ++j) { acc_ce[j] = fb; acc_ctx[j] = cb; }

    for (int pl = 0; pl < 18; ++pl) {
        float w[9];
        #pragma unroll
        for (int t = 0; t < 9; ++t) w[t] = g_fwT[(pl * 9 + t) * 64 + oc];
        float wc[9];
        const bool has_ctx = (pl >= 6 && pl < 9);
        if (has_ctx) {
            #pragma unroll
            for (int t = 0; t < 9; ++t) wc[t] = g_cwT[((pl - 6) * 9 + t) * 64 + oc];
        }
        float c0[3], c1[3], c2[3];
        #pragma unroll
        for (int r = 0; r < 3; ++r) {
            c0[r] = lds[(pl * 3 + r) * CW + px0];
            c1[r] = lds[(pl * 3 + r) * CW + px0 + 1];
        }
        #pragma unroll
        for (int j = 0; j < 16; ++j) {
            #pragma unroll
            for (int r = 0; r < 3; ++r)
                c2[r] = lds[(pl * 3 + r) * CW + px0 + j + 2];
            float a = 0.f;
            #pragma unroll
            for (int r = 0; r < 3; ++r)
                a += c0[r] * w[r * 3 + 0] + c1[r] * w[r * 3 + 1] + c2[r] * w[r * 3 + 2];
            acc_ce[j] += a;
            if (has_ctx) {
                float b2 = 0.f;
                #pragma unroll
                for (int r = 0; r < 3; ++r)
                    b2 += c0[r] * wc[r * 3 + 0] + c1[r] * wc[r * 3 + 1] + c2[r] * wc[r * 3 + 2];
                acc_ctx[j] += b2;
            }
            #pragma unroll
            for (int r = 0; r < 3; ++r) { c0[r] = c1[r]; c1[r] = c2[r]; }
        }
    }

    // relu + store conv outputs, and build per-pixel score fields:
    //   Aw[p] = Σ_oc ce[oc][p]·wnet_w[6+oc] + Σ_{c<6} sf[c][p]·wnet_w[c]; Ac analog.
    const float Wce = wnet_w[6 + oc], Cce = cnet_w[6 + oc];
    float awsel = 0.f, acsel = 0.f;
    #pragma unroll
    for (int j = 0; j < 16; ++j) {
        const float ce = fmaxf(acc_ce[j], 0.f);
        const float cx = fmaxf(acc_ctx[j], 0.f);
        const int p = py * 64 + px0 + j;
        g_ce2[(s * NPX + p) * 64 + oc] = (unsigned short)bf16_bits(ce);
        g_ct2[(s * NPX + p) * 64 + oc] = (unsigned short)bf16_bits(cx);
        float gw = ce * Wce, gc = ce * Cce;
        #pragma unroll
        for (int off = 32; off; off >>= 1) {
            gw += __shfl_xor(gw, off, 64);
            gc += __shfl_xor(gc, off, 64);
        }
        awsel = (oc == j) ? gw : awsel;
        acsel = (oc == j) ? gc : acsel;
    }
    if (oc < 16) {
        const int px = px0 + oc;
        float fwv = 0.f, fcv = 0.f;
        #pragma unroll
        for (int c = 0; c < 6; ++c) {
            const float v = lds[(c * 3 + 1) * CW + px + 1];   // center row of sf channel c
            fwv += v * wnet_w[c];
            fcv += v * cnet_w[c];
        }
        g_fld[s * NPX + py * 64 + px] = make_float2(awsel + fwv, acsel + fcv);
    }
}

// ---------------------------------------------------------------------------
// Kernel 2: epipolar softmax + interpolations, FIELD-BASED.
// wave = one (s,p); lane n<24 owns band element n (logit via gathered scalar
// field + spa/ang terms); all lanes (lane=ch) gather ce/ctx rows for mu/var
// base (2-scalar allreduce) and interp_ctx.
// ---------------------------------------------------------------------------
__global__ __launch_bounds__(256) void k_epi(
    const float* __restrict__ sv, const int* __restrict__ nxy,
    const float* __restrict__ spa, const float* __restrict__ ang,
    const float* __restrict__ wnet_w, const float* __restrict__ wnet_b,
    const float* __restrict__ cnet_w,
    float* __restrict__ out)
{
    const int blk = blockIdx.x;
    const int wid = threadIdx.x >> 6;
    const int l   = threadIdx.x & 63;
    const int s   = (blk & 7) >> 1;                       // XCD-pair swizzle
    const int p   = (blk >> 3) * 8 + (blk & 1) * 4 + wid;

    int q[NSZ];
    #pragma unroll
    for (int e = 0; e < 8; ++e) {
        int nx = nxy[((s * NPX + p) * 8 + e) * 2 + 0];
        int ny = nxy[((s * NPX + p) * 8 + e) * 2 + 1];
        nx = clampi(nx, 0, 63);
        #pragma unroll
        for (int k = 0; k < 3; ++k) {
            int y = clampi(ny + k - 1, 0, 63);
            q[e * 3 + k] = y * 64 + nx;
        }
    }

    const unsigned short* cep = g_ce2 + (size_t)s * NPX * 64;
    const unsigned short* ctp = g_ct2 + (size_t)s * NPX * 64;

    // lane = channel: ce row gathers -> mu/var -> base scalars
    float ceu[NSZ];
    #pragma unroll
    for (int n = 0; n < NSZ; ++n) ceu[n] = ldbf(cep, q[n] * 64 + l);
    float mu = 0.f;
    #pragma unroll
    for (int n = 0; n < NSZ; ++n) mu += ceu[n];
    mu *= (1.f / 24.f);
    float var = 0.f;
    #pragma unroll
    for (int n = 0; n < NSZ; ++n) { const float d = ceu[n] - mu; var += d * d; }
    var *= (1.f / 23.f);   // ddof=1

    float pw = mu * wnet_w[70 + l] + var * wnet_w[134 + l];
    float pc = mu * cnet_w[70 + l] + var * cnet_w[134 + l];
    #pragma unroll
    for (int off = 32; off; off >>= 1) {
        pw += __shfl_xor(pw, off, 64);
        pc += __shfl_xor(pc, off, 64);
    }
    const float base_w = pw, base_c = pc;

    // ctx row gathers (needed for interp_ctx after wgt known)
    float ctxu[NSZ];
    #pragma unroll
    for (int n = 0; n < NSZ; ++n) ctxu[n] = ldbf(ctp, q[n] * 64 + l);

    // lane = band element: field gather + spa/ang terms -> logit
    float Aw = 0.f, Ac = 0.f;
    if (l < NSZ) {
        const float2 A = g_fld[s * NPX + q[l]];
        Aw = A.x; Ac = A.y;
        #pragma unroll
        for (int c = 0; c < 2; ++c) {
            const float v = spa[((s * 2 + c) * NSZ + l) * NPX + p];
            Aw += v * wnet_w[198 + c];
            Ac += v * cnet_w[198 + c];
        }
        #pragma unroll
        for (int c = 0; c < 6; ++c) {
            const float v = ang[((s * 6 + c) * NSZ + l) * NPX + p];
            Aw += v * wnet_w[200 + c];
            Ac += v * cnet_w[200 + c];
        }
    }

    // softmax over the 24 active lanes
    float logit = (l < NSZ) ? (Aw + base_w + wnet_b[0]) : -1e30f;
    float mx = logit;
    #pragma unroll
    for (int off = 32; off; off >>= 1) mx = fmaxf(mx, __shfl_xor(mx, off, 64));
    float e = (l < NSZ) ? __expf(logit - mx) : 0.f;
    float ssum = e;
    #pragma unroll
    for (int off = 32; off; off >>= 1) ssum += __shfl_xor(ssum, off, 64);
    const float wgt = e / ssum;   // lane n's weight (0 for lanes >= 24)

    // confNet logit: Σ_n (Ac_n + extra_c)·wgt_n + base_c
    float clp = (l < NSZ) ? (Ac + base_c) * wgt : 0.f;   // base_c·Σwgt = base_c
    // NOTE: (Ac + base_c)*wgt summed = Σ Ac·wgt + base_c  ✓ (Σwgt = 1)
    #pragma unroll
    for (int off = 32; off; off >>= 1) clp += __shfl_xor(clp, off, 64);
    if (l == 0) g_clg[s * NPX + p] = clp;

    // out3: weight [s][p][n]
    if (l < NSZ) out[OFF3 + (s * NPX + p) * NSZ + l] = wgt;

    // broadcast all 24 weights to every lane
    float wall[NSZ];
    #pragma unroll
    for (int n = 0; n < NSZ; ++n) wall[n] = __shfl(wgt, n, 64);

    // interp_ctx channel l
    float sc = 0.f;
    #pragma unroll
    for (int n = 0; n < NSZ; ++n) sc += ctxu[n] * wall[n];
    g_vin[p * VINW + 3 + s * 64 + l] = (unsigned short)bf16_bits(sc);

    // interp_view (lanes 0..2)
    if (l < 3) {
        float svv = 0.f;
        #pragma unroll
        for (int n = 0; n < NSZ; ++n) svv += sv[(s * 3 + l) * NPX + q[n]] * wall[n];
        g_iv[(s * NPX + p) * 3 + l] = svv;
        out[OFF2 + (s * 3 + l) * NPX + p] = svv;
    }
}

// ---------------------------------------------------------------------------
// Kernel 3: confNet softmax over sources + blended image. 1 thread / pixel.
// ---------------------------------------------------------------------------
__global__ __launch_bounds__(64) void k_conf(
    const float* __restrict__ cnet_b, float* __restrict__ out)
{
    const int p = blockIdx.x * 64 + threadIdx.x;
    const float cb = cnet_b[0];

    float lg[NS];
    #pragma unroll
    for (int s = 0; s < NS; ++s) lg[s] = g_clg[s * NPX + p] + cb;
    float m = lg[0];
    #pragma unroll
    for (int s = 1; s < NS; ++s) m = fmaxf(m, lg[s]);
    float ssum = 0.f;
    float conf[NS];
    #pragma unroll
    for (int s = 0; s < NS; ++s) { conf[s] = __expf(lg[s] - m); ssum += conf[s]; }
    const float inv = 1.f / ssum;
    #pragma unroll
    for (int s = 0; s < NS; ++s) {
        conf[s] *= inv;
        out[OFF4 + s * NPX + p] = conf[s];
    }
    #pragma unroll
    for (int c = 0; c < 3; ++c) {
        float acc = 0.f;
        #pragma unroll
        for (int s = 0; s < NS; ++s)
            acc += g_iv[(s * NPX + p) * 3 + c] * conf[s];
        g_bl[c * NPX + p] = acc;
        g_vin[p * VINW + c] = (unsigned short)bf16_bits(acc);
        out[OFF1 + c * NPX + p] = acc;
    }
}

// ---------------------------------------------------------------------------
// Kernel 4: psvNet, ROW-TILED. block = (s, py): 256 threads = 4 waves,
// wave -> 16 px, lane = oc. Planes 0..23 = psv (ic*8+d), 24..26 = blended ic.
// ---------------------------------------------------------------------------
__global__ __launch_bounds__(256) void k_psv(
    const float* __restrict__ psvs, const float* __restrict__ psv_b)
{
    __shared__ float lds[27 * 3 * CW];
    const int s  = blockIdx.x >> 6, py = blockIdx.x & 63;
    const int tid = threadIdx.x;

    for (int i = tid; i < 27 * 3 * CW; i += 256) lds[i] = 0.f;
    __syncthreads();
    for (int i = tid; i < 27 * 3 * 64; i += 256) {
        const int col = i & 63;
        const int r   = (i >> 6) % 3;
        const int pl  = i / 192;
        const int iy  = py + r - 1;
        if ((unsigned)iy < 64u) {
            const float* src = (pl < 24) ? (psvs + (s * 24 + pl) * NPX)
                                         : (g_bl + (pl - 24) * NPX);
            lds[(pl * 3 + r) * CW + col + 1] = src[iy * 64 + col];
        }
    }
    __syncthreads();

    const int oc  = tid & 63;
    const int px0 = (tid >> 6) * 16;
    const float bias = psv_b[oc];

    float wp[3][9];
    #pragma unroll
    for (int ic = 0; ic < 3; ++ic)
        #pragma unroll
        for (int t = 0; t < 9; ++t) wp[ic][t] = g_pwT[(ic * 9 + t) * 64 + oc];

    float bconst[16];
    #pragma unroll
    for (int j = 0; j < 16; ++j) bconst[j] = bias;
    for (int ic = 0; ic < 3; ++ic) {
        float w[9];
        #pragma unroll
        for (int t = 0; t < 9; ++t) w[t] = g_pwT[((3 + ic) * 9 + t) * 64 + oc];
        const int pl = 24 + ic;
        float c0[3], c1[3], c2[3];
        #pragma unroll
        for (int r = 0; r < 3; ++r) {
            c0[r] = lds[(pl * 3 + r) * CW + px0];
            c1[r] = lds[(pl * 3 + r) * CW + px0 + 1];
        }
        #pragma unroll
        for (int j = 0; j < 16; ++j) {
            #pragma unroll
            for (int r = 0; r < 3; ++r)
                c2[r] = lds[(pl * 3 + r) * CW + px0 + j + 2];
            float a = 0.f;
            #pragma unroll
            for (int r = 0; r < 3; ++r)
                a += c0[r] * w[r * 3 + 0] + c1[r] * w[r * 3 + 1] + c2[r] * w[r * 3 + 2];
            bconst[j] += a;
            #pragma unroll
            for (int r = 0; r < 3; ++r) { c0[r] = c1[r]; c1[r] = c2[r]; }
        }
    }

    float acc[16];
    #pragma unroll
    for (int j = 0; j < 16; ++j) acc[j] = 0.f;

    for (int d = 0; d < 8; ++d) {
        float a[16];
        #pragma unroll
        for (int j = 0; j < 16; ++j) a[j] = bconst[j];
        #pragma unroll
        for (int ic = 0; ic < 3; ++ic) {
            const int pl = ic * 8 + d;
            float c0[3], c1[3], c2[3];
            #pragma unroll
            for (int r = 0; r < 3; ++r) {
                c0[r] = lds[(pl * 3 + r) * CW + px0];
                c1[r] = lds[(pl * 3 + r) * CW + px0 + 1];
            }
            #pragma unroll
            for (int j = 0; j < 16; ++j) {
                #pragma unroll
                for (int r = 0; r < 3; ++r)
                    c2[r] = lds[(pl * 3 + r) * CW + px0 + j + 2];
                float t2 = 0.f;
                #pragma unroll
                for (int r = 0; r < 3; ++r)
                    t2 += c0[r] * wp[ic][r * 3 + 0] + c1[r] * wp[ic][r * 3 + 1] + c2[r] * wp[ic][r * 3 + 2];
                a[j] += t2;
                #pragma unroll
                for (int r = 0; r < 3; ++r) { c0[r] = c1[r]; c1[r] = c2[r]; }
            }
        }
        #pragma unroll
        for (int j = 0; j < 16; ++j) acc[j] += fmaxf(a[j], 0.f);
    }
    #pragma unroll
    for (int j = 0; j < 16; ++j)
        g_vin[(py * 64 + px0 + j) * VINW + 259 + s * 64 + oc] =
            (unsigned short)bf16_bits(acc[j] * 0.125f);
}

// ---------------------------------------------------------------------------
// Kernel 5: vref conv3x3 over 515 channels (g_vin, bf16) -> 3. grid 4096, block 64.
// ---------------------------------------------------------------------------
__global__ __launch_bounds__(64) void k_vref(
    const float* __restrict__ vref_b, float* __restrict__ out)
{
    const int p = blockIdx.x;
    const int py = p >> 6, px = p & 63;
    const int l = threadIdx.x;

    float acc[3] = {0.f, 0.f, 0.f};
    #pragma unroll
    for (int k = 0; k < 9; ++k) {
        const int ch = k * 64 + l;
        if (ch >= 515) break;
        #pragma unroll
        for (int t = 0; t < 9; ++t) {
            const int iy = py + t / 3 - 1, ix = px + t % 3 - 1;
            if ((unsigned)iy >= 64u || (unsigned)ix >= 64u) continue;
            const float v = ldbf(g_vin, (iy * 64 + ix) * VINW + ch);
            #pragma unroll
            for (int oc = 0; oc < 3; ++oc)
                acc[oc] += v * ldbf(g_vwT, (oc * 9 + t) * 515 + ch);
        }
    }
    #pragma unroll
    for (int off = 32; off; off >>= 1) {
        #pragma unroll
        for (int oc = 0; oc < 3; ++oc)
            acc[oc] += __shfl_xor(acc[oc], off, 64);
    }
    if (l == 0) {
        #pragma unroll
        for (int oc = 0; oc < 3; ++oc)
            out[OFF0 + oc * NPX + p] = acc[oc] + vref_b[oc];
    }
}

// ---------------------------------------------------------------------------
extern "C" void kernel_launch(void* const* d_in, const int* in_sizes, int n_in,
                              void* d_out, int out_size, void* d_ws, size_t ws_size,
                              hipStream_t stream)
{
    auto find1 = [&](int sz, int fb) -> int {
        for (int i = 0; i < n_in; ++i) if (in_sizes[i] == sz) return i;
        return fb;
    };
    const int i_sv  = find1(49152, 0);
    const int i_sf  = find1(98304, 1);
    const int i_psv = find1(393216, 2);
    const int i_wv  = find1(147456, 3);
    const int i_nxy = find1(262144, 5);
    const int i_spa = find1(786432, 6);
    const int i_ang = find1(2359296, 7);
    const int i_fw  = find1(10368, 9);
    const int i_cw  = find1(1728, 11);
    const int i_pw  = find1(3456, 17);
    const int i_vw  = find1(13905, 19);
    const int i_vb  = find1(3, 20);
    int i_ww = -1, i_cnw = -1;
    for (int i = 0; i < n_in; ++i)
        if (in_sizes[i] == 206) { if (i_ww < 0) i_ww = i; else { i_cnw = i; break; } }
    if (i_ww  < 0) i_ww  = 13;
    if (i_cnw < 0) i_cnw = 15;
    int b64[3] = {10, 12, 18}; int c64 = 0;
    for (int i = 0; i < n_in && c64 < 3; ++i) if (in_sizes[i] == 64) b64[c64++] = i;
    const int i_fb = b64[0], i_cb = b64[1], i_pb = b64[2];
    int i_wb = -1, i_cnb = -1;
    for (int i = i_fw + 1; i < n_in; ++i)
        if (in_sizes[i] == 1) { if (i_wb < 0) i_wb = i; else { i_cnb = i; break; } }
    if (i_wb  < 0) i_wb  = 14;
    if (i_cnb < 0) i_cnb = 16;

    const float* sv     = (const float*)d_in[i_sv];
    const float* sf     = (const float*)d_in[i_sf];
    const float* psvs   = (const float*)d_in[i_psv];
    const float* wv     = (const float*)d_in[i_wv];
    const int*   nxy    = (const int*)d_in[i_nxy];
    const float* spa    = (const float*)d_in[i_spa];
    const float* ang    = (const float*)d_in[i_ang];
    const float* flow_w = (const float*)d_in[i_fw];
    const float* flow_b = (const float*)d_in[i_fb];
    const float* ctx_w  = (const float*)d_in[i_cw];
    const float* ctx_b  = (const float*)d_in[i_cb];
    const float* wnet_w = (const float*)d_in[i_ww];
    const float* wnet_b = (const float*)d_in[i_wb];
    const float* cnet_w = (const float*)d_in[i_cnw];
    const float* cnet_b = (const float*)d_in[i_cnb];
    const float* psv_w  = (const float*)d_in[i_pw];
    const float* psv_b  = (const float*)d_in[i_pb];
    const float* vref_w = (const float*)d_in[i_vw];
    const float* vref_b = (const float*)d_in[i_vb];
    (void)d_ws; (void)ws_size; (void)out_size;

    float* out = (float*)d_out;

    k_prep <<<64, 256, 0, stream>>>(flow_w, ctx_w, psv_w, vref_w);
    k_convs<<<256, 256, 0, stream>>>(sv, sf, wv, flow_b, ctx_b, wnet_w, cnet_w);
    k_epi  <<<4096, 256, 0, stream>>>(sv, nxy, spa, ang, wnet_w, wnet_b, cnet_w, out);
    k_conf <<<64, 64, 0, stream>>>(cnet_b, out);
    k_psv  <<<256, 256, 0, stream>>>(psvs, psv_b);
    k_vref <<<4096, 64, 0, stream>>>(vref_b, out);
}

// Round 12
// 200.339 us; speedup vs baseline: 1.1890x; 1.0999x over previous
//
#include <hip/hip_runtime.h>
#include <hip/hip_bf16.h>

// Inputs/outputs are f32 (proven: round-5 bf16 -> NaN; rounds 4/6 passed on f32 path).

// problem constants (fixed by harness shapes)
#define NS   4
#define NPX  4096
#define NSZ  24
#define PS   64
#define VINW 520   // ch map: 0-255 ictx, 256-511 pf, 512-514 blended, 515-519 pad
#define CW   66    // LDS row width: 64 cols + 2-col zero halo

// out element offsets
#define OFF0 0        // ref_novel_view (3,4096)
#define OFF1 12288    // blended_img    (3,4096)
#define OFF2 24576    // interp_view    (4,3,4096)
#define OFF3 73728    // weight         (4,4096,24)
#define OFF4 466944   // confs          (4,4096)

// ---------------------------------------------------------------------------
// Static device-global scratch.
// g_cc packs ce (lo bf16) + ctx (hi bf16): 4 MB total, L2-resident per source
// with the XCD swizzle; ONE dword gather per band element serves both.
// g_fld[s][p] = (Aw, Ac): per-pixel score fields (linearized channel dots).
// ---------------------------------------------------------------------------
__device__ unsigned g_cc [NS * NPX * 64];   // [s][p][ch]: lo=ce, hi=ctx (bf16)
__device__ float2 g_fld[NS * NPX];
__device__ unsigned short g_vin [NPX * VINW];  // bf16, 16B-aligned lane groups
__device__ float g_iv  [NS * NPX * 3];    // [s][p][c]
__device__ float g_clg [NS * NPX];        // confNet logit per (source,pixel)
__device__ float g_bl  [3 * NPX];         // blended, channel-plane (f32)
// transposed weights (lane-coalesced on the fast index)
__device__ float g_fwT [162 * 64];        // [(ic*9+t)][oc]
__device__ float g_cwT [27 * 64];         // [(ic*9+t)][oc]
__device__ float g_pwT [54 * 64];         // [(ic*9+t)][oc]
__device__ unsigned short g_vwT [3 * 9 * VINW];  // bf16 [(oc*9+t)][nch], remapped

__device__ __forceinline__ int clampi(int v, int lo, int hi) {
    return v < lo ? lo : (v > hi ? hi : v);
}
__device__ __forceinline__ unsigned bf16_bits(float f) {   // RNE f32->bf16 bits
    unsigned u = __float_as_uint(f);
    return (u + 0x7fffu + ((u >> 16) & 1u)) >> 16;
}
__device__ __forceinline__ float bf16_lo(unsigned v) { return __uint_as_float(v << 16); }
__device__ __forceinline__ float bf16_hi(unsigned v) { return __uint_as_float(v & 0xffff0000u); }
__device__ __forceinline__ float ldbf(const unsigned short* p, int i) {
    return __uint_as_float(((unsigned)p[i]) << 16);
}

// ---------------------------------------------------------------------------
// Kernel 0: weight transposes (same work every call).
// ---------------------------------------------------------------------------
__global__ void k_prep(const float* __restrict__ fw, const float* __restrict__ cw,
                       const float* __restrict__ pw, const float* __restrict__ vw)
{
    const int i = blockIdx.x * 256 + threadIdx.x;
    const int stride = gridDim.x * 256;
    for (int d = i; d < 162 * 64; d += stride) g_fwT[d] = fw[(d & 63) * 162 + (d >> 6)];
    for (int d = i; d < 27 * 64;  d += stride) g_cwT[d] = cw[(d & 63) * 27  + (d >> 6)];
    for (int d = i; d < 54 * 64;  d += stride) g_pwT[d] = pw[(d & 63) * 54  + (d >> 6)];
    for (int d = i; d < 3 * 9 * VINW; d += stride) {
        const int oc = d / (9 * VINW), rem = d % (9 * VINW);
        const int t = rem / VINW, nch = rem % VINW;
        // nch map: 0-255 ictx -> orig 3+nch; 256-511 pf -> orig 259+(nch-256);
        //          512-514 blended -> orig nch-512; 515+ pad -> 0
        float v = 0.f;
        if (nch < 256)      v = vw[(oc * 515 + 3 + nch) * 9 + t];
        else if (nch < 512) v = vw[(oc * 515 + 259 + (nch - 256)) * 9 + t];
        else if (nch < 515) v = vw[(oc * 515 + (nch - 512)) * 9 + t];
        g_vwT[d] = (unsigned short)bf16_bits(v);
    }
}

// ---------------------------------------------------------------------------
// Kernel 1: flowRefNet + ctxNet convs, ROW-TILED, + per-pixel score fields.
// block = (s, py): 256 threads = 4 waves; wave w -> px in [16w,16w+16), lane = oc.
// ---------------------------------------------------------------------------
__global__ __launch_bounds__(256) void k_convs(
    const float* __restrict__ sv, const float* __restrict__ sf, const float* __restrict__ wv,
    const float* __restrict__ flow_b, const float* __restrict__ ctx_b,
    const float* __restrict__ wnet_w, const float* __restrict__ cnet_w)
{
    __shared__ float lds[18 * 3 * CW];
    const int s  = blockIdx.x >> 6, py = blockIdx.x & 63;
    const int tid = threadIdx.x;

    for (int i = tid; i < 18 * 3 * CW; i += 256) lds[i] = 0.f;
    __syncthreads();
    for (int i = tid; i < 18 * 3 * 64; i += 256) {
        const int col = i & 63;
        const int r   = (i >> 6) % 3;
        const int pl  = i / 192;
        const int iy  = py + r - 1;
        if ((unsigned)iy < 64u) {
            const float* src = (pl < 6) ? (sf + (s * 6 + pl) * NPX)
                             : (pl < 9) ? (sv + (s * 3 + (pl - 6)) * NPX)
                                        : (wv + (s * 9 + (pl - 9)) * NPX);
            lds[(pl * 3 + r) * CW + col + 1] = src[iy * 64 + col];
        }
    }
    __syncthreads();

    const int oc  = tid & 63;
    const int px0 = (tid >> 6) * 16;

    float acc_ce[16], acc_ctx[16];
    const float fb = flow_b[oc], cb = ctx_b[oc];
    #pragma unroll
    for (int j = 0; j < 16; ++j) { acc_ce[j] = fb; acc_ctx[j] = cb; }

    for (int pl = 0; pl < 18; ++pl) {
        float w[9];
        #pragma unroll
        for (int t = 0; t < 9; ++t) w[t] = g_fwT[(pl * 9 + t) * 64 + oc];
        float wc[9];
        const bool has_ctx = (pl >= 6 && pl < 9);
        if (has_ctx) {
            #pragma unroll
            for (int t = 0; t < 9; ++t) wc[t] = g_cwT[((pl - 6) * 9 + t) * 64 + oc];
        }
        float c0[3], c1[3], c2[3];
        #pragma unroll
        for (int r = 0; r < 3; ++r) {
            c0[r] = lds[(pl * 3 + r) * CW + px0];
            c1[r] = lds[(pl * 3 + r) * CW + px0 + 1];
        }
        #pragma unroll
        for (int j = 0; j < 16; ++j) {
            #pragma unroll
            for (int r = 0; r < 3; ++r)
                c2[r] = lds[(pl * 3 + r) * CW + px0 + j + 2];
            float a = 0.f;
            #pragma unroll
            for (int r = 0; r < 3; ++r)
                a += c0[r] * w[r * 3 + 0] + c1[r] * w[r * 3 + 1] + c2[r] * w[r * 3 + 2];
            acc_ce[j] += a;
            if (has_ctx) {
                float b2 = 0.f;
                #pragma unroll
                for (int r = 0; r < 3; ++r)
                    b2 += c0[r] * wc[r * 3 + 0] + c1[r] * wc[r * 3 + 1] + c2[r] * wc[r * 3 + 2];
                acc_ctx[j] += b2;
            }
            #pragma unroll
            for (int r = 0; r < 3; ++r) { c0[r] = c1[r]; c1[r] = c2[r]; }
        }
    }

    // relu + packed store + per-pixel score fields (Aw/Ac)
    const float Wce = wnet_w[6 + oc], Cce = cnet_w[6 + oc];
    float awsel = 0.f, acsel = 0.f;
    #pragma unroll
    for (int j = 0; j < 16; ++j) {
        const float ce = fmaxf(acc_ce[j], 0.f);
        const float cx = fmaxf(acc_ctx[j], 0.f);
        const int p = py * 64 + px0 + j;
        g_cc[(s * NPX + p) * 64 + oc] = bf16_bits(ce) | (bf16_bits(cx) << 16);
        float gw = ce * Wce, gc = ce * Cce;
        #pragma unroll
        for (int off = 32; off; off >>= 1) {
            gw += __shfl_xor(gw, off, 64);
            gc += __shfl_xor(gc, off, 64);
        }
        awsel = (oc == j) ? gw : awsel;
        acsel = (oc == j) ? gc : acsel;
    }
    if (oc < 16) {
        const int px = px0 + oc;
        float fwv = 0.f, fcv = 0.f;
        #pragma unroll
        for (int c = 0; c < 6; ++c) {
            const float v = lds[(c * 3 + 1) * CW + px + 1];   // center row of sf ch c
            fwv += v * wnet_w[c];
            fcv += v * cnet_w[c];
        }
        g_fld[s * NPX + py * 64 + px] = make_float2(awsel + fwv, acsel + fcv);
    }
}

// ---------------------------------------------------------------------------
// Kernel 2: epipolar softmax + interpolations, FIELD-BASED, packed gathers.
// wave = one (s,p); 24 dword gathers give ce (lo) AND ctx (hi).
// ---------------------------------------------------------------------------
__global__ __launch_bounds__(256) void k_epi(
    const float* __restrict__ sv, const int* __restrict__ nxy,
    const float* __restrict__ spa, const float* __restrict__ ang,
    const float* __restrict__ wnet_w, const float* __restrict__ wnet_b,
    const float* __restrict__ cnet_w,
    float* __restrict__ out)
{
    const int blk = blockIdx.x;
    const int wid = threadIdx.x >> 6;
    const int l   = threadIdx.x & 63;
    const int s   = (blk & 7) >> 1;                       // XCD-pair swizzle
    const int p   = (blk >> 3) * 8 + (blk & 1) * 4 + wid;

    int q[NSZ];
    #pragma unroll
    for (int e = 0; e < 8; ++e) {
        int nx = nxy[((s * NPX + p) * 8 + e) * 2 + 0];
        int ny = nxy[((s * NPX + p) * 8 + e) * 2 + 1];
        nx = clampi(nx, 0, 63);
        #pragma unroll
        for (int k = 0; k < 3; ++k) {
            int y = clampi(ny + k - 1, 0, 63);
            q[e * 3 + k] = y * 64 + nx;
        }
    }

    const unsigned* ccp = g_cc + (size_t)s * NPX * 64;
    unsigned cc[NSZ];
    #pragma unroll
    for (int n = 0; n < NSZ; ++n) cc[n] = ccp[q[n] * 64 + l];

    // lane = channel: mu/var -> base scalars (2-scalar allreduce)
    float mu = 0.f;
    #pragma unroll
    for (int n = 0; n < NSZ; ++n) mu += bf16_lo(cc[n]);
    mu *= (1.f / 24.f);
    float var = 0.f;
    #pragma unroll
    for (int n = 0; n < NSZ; ++n) { const float d = bf16_lo(cc[n]) - mu; var += d * d; }
    var *= (1.f / 23.f);   // ddof=1

    float pw = mu * wnet_w[70 + l] + var * wnet_w[134 + l];
    float pc = mu * cnet_w[70 + l] + var * cnet_w[134 + l];
    #pragma unroll
    for (int off = 32; off; off >>= 1) {
        pw += __shfl_xor(pw, off, 64);
        pc += __shfl_xor(pc, off, 64);
    }
    const float base_w = pw, base_c = pc;

    // lane = band element: field gather + spa/ang terms -> logit
    float Aw = 0.f, Ac = 0.f;
    if (l < NSZ) {
        const float2 A = g_fld[s * NPX + q[l]];
        Aw = A.x; Ac = A.y;
        #pragma unroll
        for (int c = 0; c < 2; ++c) {
            const float v = spa[((s * 2 + c) * NSZ + l) * NPX + p];
            Aw += v * wnet_w[198 + c];
            Ac += v * cnet_w[198 + c];
        }
        #pragma unroll
        for (int c = 0; c < 6; ++c) {
            const float v = ang[((s * 6 + c) * NSZ + l) * NPX + p];
            Aw += v * wnet_w[200 + c];
            Ac += v * cnet_w[200 + c];
        }
    }

    // softmax over the 24 active lanes
    float logit = (l < NSZ) ? (Aw + base_w + wnet_b[0]) : -1e30f;
    float mx = logit;
    #pragma unroll
    for (int off = 32; off; off >>= 1) mx = fmaxf(mx, __shfl_xor(mx, off, 64));
    float e = (l < NSZ) ? __expf(logit - mx) : 0.f;
    float ssum = e;
    #pragma unroll
    for (int off = 32; off; off >>= 1) ssum += __shfl_xor(ssum, off, 64);
    const float wgt = e / ssum;

    // confNet logit (Σwgt = 1 makes the base additive)
    float clp = (l < NSZ) ? (Ac + base_c) * wgt : 0.f;
    #pragma unroll
    for (int off = 32; off; off >>= 1) clp += __shfl_xor(clp, off, 64);
    if (l == 0) g_clg[s * NPX + p] = clp;

    // out3: weight [s][p][n]
    if (l < NSZ) out[OFF3 + (s * NPX + p) * NSZ + l] = wgt;

    // broadcast all 24 weights
    float wall[NSZ];
    #pragma unroll
    for (int n = 0; n < NSZ; ++n) wall[n] = __shfl(wgt, n, 64);

    // interp_ctx channel l (hi halves of the same gathered dwords)
    float sc = 0.f;
    #pragma unroll
    for (int n = 0; n < NSZ; ++n) sc += bf16_hi(cc[n]) * wall[n];
    g_vin[p * VINW + s * 64 + l] = (unsigned short)bf16_bits(sc);   // ictx base 0

    // interp_view (lanes 0..2)
    if (l < 3) {
        float svv = 0.f;
        #pragma unroll
        for (int n = 0; n < NSZ; ++n) svv += sv[(s * 3 + l) * NPX + q[n]] * wall[n];
        g_iv[(s * NPX + p) * 3 + l] = svv;
        out[OFF2 + (s * 3 + l) * NPX + p] = svv;
    }
}

// ---------------------------------------------------------------------------
// Kernel 3: confNet softmax over sources + blended image. 1 thread / pixel.
// ---------------------------------------------------------------------------
__global__ __launch_bounds__(64) void k_conf(
    const float* __restrict__ cnet_b, float* __restrict__ out)
{
    const int p = blockIdx.x * 64 + threadIdx.x;
    const float cb = cnet_b[0];

    float lg[NS];
    #pragma unroll
    for (int s = 0; s < NS; ++s) lg[s] = g_clg[s * NPX + p] + cb;
    float m = lg[0];
    #pragma unroll
    for (int s = 1; s < NS; ++s) m = fmaxf(m, lg[s]);
    float ssum = 0.f;
    float conf[NS];
    #pragma unroll
    for (int s = 0; s < NS; ++s) { conf[s] = __expf(lg[s] - m); ssum += conf[s]; }
    const float inv = 1.f / ssum;
    #pragma unroll
    for (int s = 0; s < NS; ++s) {
        conf[s] *= inv;
        out[OFF4 + s * NPX + p] = conf[s];
    }
    #pragma unroll
    for (int c = 0; c < 3; ++c) {
        float acc = 0.f;
        #pragma unroll
        for (int s = 0; s < NS; ++s)
            acc += g_iv[(s * NPX + p) * 3 + c] * conf[s];
        g_bl[c * NPX + p] = acc;
        g_vin[p * VINW + 512 + c] = (unsigned short)bf16_bits(acc);  // blended base 512
        out[OFF1 + c * NPX + p] = acc;
    }
}

// ---------------------------------------------------------------------------
// Kernel 4: psvNet, ROW-TILED. block = (s, py): 256 threads = 4 waves,
// wave -> 16 px, lane = oc. Planes 0..23 = psv (ic*8+d), 24..26 = blended ic.
// ---------------------------------------------------------------------------
__global__ __launch_bounds__(256) void k_psv(
    const float* __restrict__ psvs, const float* __restrict__ psv_b)
{
    __shared__ float lds[27 * 3 * CW];
    const int s  = blockIdx.x >> 6, py = blockIdx.x & 63;
    const int tid = threadIdx.x;

    for (int i = tid; i < 27 * 3 * CW; i += 256) lds[i] = 0.f;
    __syncthreads();
    for (int i = tid; i < 27 * 3 * 64; i += 256) {
        const int col = i & 63;
        const int r   = (i >> 6) % 3;
        const int pl  = i / 192;
        const int iy  = py + r - 1;
        if ((unsigned)iy < 64u) {
            const float* src = (pl < 24) ? (psvs + (s * 24 + pl) * NPX)
                                         : (g_bl + (pl - 24) * NPX);
            lds[(pl * 3 + r) * CW + col + 1] = src[iy * 64 + col];
        }
    }
    __syncthreads();

    const int oc  = tid & 63;
    const int px0 = (tid >> 6) * 16;
    const float bias = psv_b[oc];

    float wp[3][9];
    #pragma unroll
    for (int ic = 0; ic < 3; ++ic)
        #pragma unroll
        for (int t = 0; t < 9; ++t) wp[ic][t] = g_pwT[(ic * 9 + t) * 64 + oc];

    float bconst[16];
    #pragma unroll
    for (int j = 0; j < 16; ++j) bconst[j] = bias;
    for (int ic = 0; ic < 3; ++ic) {
        float w[9];
        #pragma unroll
        for (int t = 0; t < 9; ++t) w[t] = g_pwT[((3 + ic) * 9 + t) * 64 + oc];
        const int pl = 24 + ic;
        float c0[3], c1[3], c2[3];
        #pragma unroll
        for (int r = 0; r < 3; ++r) {
            c0[r] = lds[(pl * 3 + r) * CW + px0];
            c1[r] = lds[(pl * 3 + r) * CW + px0 + 1];
        }
        #pragma unroll
        for (int j = 0; j < 16; ++j) {
            #pragma unroll
            for (int r = 0; r < 3; ++r)
                c2[r] = lds[(pl * 3 + r) * CW + px0 + j + 2];
            float a = 0.f;
            #pragma unroll
            for (int r = 0; r < 3; ++r)
                a += c0[r] * w[r * 3 + 0] + c1[r] * w[r * 3 + 1] + c2[r] * w[r * 3 + 2];
            bconst[j] += a;
            #pragma unroll
            for (int r = 0; r < 3; ++r) { c0[r] = c1[r]; c1[r] = c2[r]; }
        }
    }

    float acc[16];
    #pragma unroll
    for (int j = 0; j < 16; ++j) acc[j] = 0.f;

    for (int d = 0; d < 8; ++d) {
        float a[16];
        #pragma unroll
        for (int j = 0; j < 16; ++j) a[j] = bconst[j];
        #pragma unroll
        for (int ic = 0; ic < 3; ++ic) {
            const int pl = ic * 8 + d;
            float c0[3], c1[3], c2[3];
            #pragma unroll
            for (int r = 0; r < 3; ++r) {
                c0[r] = lds[(pl * 3 + r) * CW + px0];
                c1[r] = lds[(pl * 3 + r) * CW + px0 + 1];
            }
            #pragma unroll
            for (int j = 0; j < 16; ++j) {
                #pragma unroll
                for (int r = 0; r < 3; ++r)
                    c2[r] = lds[(pl * 3 + r) * CW + px0 + j + 2];
                float t2 = 0.f;
                #pragma unroll
                for (int r = 0; r < 3; ++r)
                    t2 += c0[r] * wp[ic][r * 3 + 0] + c1[r] * wp[ic][r * 3 + 1] + c2[r] * wp[ic][r * 3 + 2];
                a[j] += t2;
                #pragma unroll
                for (int r = 0; r < 3; ++r) { c0[r] = c1[r]; c1[r] = c2[r]; }
            }
        }
        #pragma unroll
        for (int j = 0; j < 16; ++j) acc[j] += fmaxf(a[j], 0.f);
    }
    #pragma unroll
    for (int j = 0; j < 16; ++j)
        g_vin[(py * 64 + px0 + j) * VINW + 256 + s * 64 + oc] =      // pf base 256
            (unsigned short)bf16_bits(acc[j] * 0.125f);
}

// ---------------------------------------------------------------------------
// Kernel 5: vref conv3x3 over 515 channels -> 3, VECTORIZED.
// lane l owns channels [8l, 8l+8): one uint4 (8 bf16) g_vin load per tap and
// one uint4 weight load per (oc,tap). Blended chs 512-514 on lanes 0-2 scalar.
// ---------------------------------------------------------------------------
__global__ __launch_bounds__(64) void k_vref(
    const float* __restrict__ vref_b, float* __restrict__ out)
{
    const int p = blockIdx.x;
    const int py = p >> 6, px = p & 63;
    const int l = threadIdx.x;

    float acc[3] = {0.f, 0.f, 0.f};
    #pragma unroll
    for (int t = 0; t < 9; ++t) {
        const int iy = py + t / 3 - 1, ix = px + t % 3 - 1;
        if ((unsigned)iy >= 64u || (unsigned)ix >= 64u) continue;
        const int rowbase = (iy * 64 + ix) * VINW;
        const uint4 vv = *(const uint4*)(g_vin + rowbase + 8 * l);
        float v[8];
        v[0] = bf16_lo(vv.x); v[1] = bf16_hi(vv.x);
        v[2] = bf16_lo(vv.y); v[3] = bf16_hi(vv.y);
        v[4] = bf16_lo(vv.z); v[5] = bf16_hi(vv.z);
        v[6] = bf16_lo(vv.w); v[7] = bf16_hi(vv.w);
        #pragma unroll
        for (int oc = 0; oc < 3; ++oc) {
            const uint4 ww = *(const uint4*)(g_vwT + (oc * 9 + t) * VINW + 8 * l);
            acc[oc] += v[0] * bf16_lo(ww.x) + v[1] * bf16_hi(ww.x)
                     + v[2] * bf16_lo(ww.y) + v[3] * bf16_hi(ww.y)
                     + v[4] * bf16_lo(ww.z) + v[5] * bf16_hi(ww.z)
                     + v[6] * bf16_lo(ww.w) + v[7] * bf16_hi(ww.w);
        }
        if (l < 3) {   // blended channels 512-514
            const float bv = ldbf(g_vin, rowbase + 512 + l);
            #pragma unroll
            for (int oc = 0; oc < 3; ++oc)
                acc[oc] += bv * ldbf(g_vwT, (oc * 9 + t) * VINW + 512 + l);
        }
    }
    #pragma unroll
    for (int off = 32; off; off >>= 1) {
        #pragma unroll
        for (int oc = 0; oc < 3; ++oc)
            acc[oc] += __shfl_xor(acc[oc], off, 64);
    }
    if (l == 0) {
        #pragma unroll
        for (int oc = 0; oc < 3; ++oc)
            out[OFF0 + oc * NPX + p] = acc[oc] + vref_b[oc];
    }
}

// ---------------------------------------------------------------------------
extern "C" void kernel_launch(void* const* d_in, const int* in_sizes, int n_in,
                              void* d_out, int out_size, void* d_ws, size_t ws_size,
                              hipStream_t stream)
{
    auto find1 = [&](int sz, int fb) -> int {
        for (int i = 0; i < n_in; ++i) if (in_sizes[i] == sz) return i;
        return fb;
    };
    const int i_sv  = find1(49152, 0);
    const int i_sf  = find1(98304, 1);
    const int i_psv = find1(393216, 2);
    const int i_wv  = find1(147456, 3);
    const int i_nxy = find1(262144, 5);
    const int i_spa = find1(786432, 6);
    const int i_ang = find1(2359296, 7);
    const int i_fw  = find1(10368, 9);
    const int i_cw  = find1(1728, 11);
    const int i_pw  = find1(3456, 17);
    const int i_vw  = find1(13905, 19);
    const int i_vb  = find1(3, 20);
    int i_ww = -1, i_cnw = -1;
    for (int i = 0; i < n_in; ++i)
        if (in_sizes[i] == 206) { if (i_ww < 0) i_ww = i; else { i_cnw = i; break; } }
    if (i_ww  < 0) i_ww  = 13;
    if (i_cnw < 0) i_cnw = 15;
    int b64[3] = {10, 12, 18}; int c64 = 0;
    for (int i = 0; i < n_in && c64 < 3; ++i) if (in_sizes[i] == 64) b64[c64++] = i;
    const int i_fb = b64[0], i_cb = b64[1], i_pb = b64[2];
    int i_wb = -1, i_cnb = -1;
    for (int i = i_fw + 1; i < n_in; ++i)
        if (in_sizes[i] == 1) { if (i_wb < 0) i_wb = i; else { i_cnb = i; break; } }
    if (i_wb  < 0) i_wb  = 14;
    if (i_cnb < 0) i_cnb = 16;

    const float* sv     = (const float*)d_in[i_sv];
    const float* sf     = (const float*)d_in[i_sf];
    const float* psvs   = (const float*)d_in[i_psv];
    const float* wv     = (const float*)d_in[i_wv];
    const int*   nxy    = (const int*)d_in[i_nxy];
    const float* spa    = (const float*)d_in[i_spa];
    const float* ang    = (const float*)d_in[i_ang];
    const float* flow_w = (const float*)d_in[i_fw];
    const float* flow_b = (const float*)d_in[i_fb];
    const float* ctx_w  = (const float*)d_in[i_cw];
    const float* ctx_b  = (const float*)d_in[i_cb];
    const float* wnet_w = (const float*)d_in[i_ww];
    const float* wnet_b = (const float*)d_in[i_wb];
    const float* cnet_w = (const float*)d_in[i_cnw];
    const float* cnet_b = (const float*)d_in[i_cnb];
    const float* psv_w  = (const float*)d_in[i_pw];
    const float* psv_b  = (const float*)d_in[i_pb];
    const float* vref_w = (const float*)d_in[i_vw];
    const float* vref_b = (const float*)d_in[i_vb];
    (void)d_ws; (void)ws_size; (void)out_size;

    float* out = (float*)d_out;

    k_prep <<<64, 256, 0, stream>>>(flow_w, ctx_w, psv_w, vref_w);
    k_convs<<<256, 256, 0, stream>>>(sv, sf, wv, flow_b, ctx_b, wnet_w, cnet_w);
    k_epi  <<<4096, 256, 0, stream>>>(sv, nxy, spa, ang, wnet_w, wnet_b, cnet_w, out);
    k_conf <<<64, 64, 0, stream>>>(cnet_b, out);
    k_psv  <<<256, 256, 0, stream>>>(psvs, psv_b);
    k_vref <<<4096, 64, 0, stream>>>(vref_b, out);
}

// Round 13
// 175.287 us; speedup vs baseline: 1.3589x; 1.1429x over previous
//
#include <hip/hip_runtime.h>
#include <hip/hip_bf16.h>

// Inputs/outputs are f32 (proven: round-5 bf16 -> NaN; rounds 4/6 passed on f32 path).

// problem constants (fixed by harness shapes)
#define NS   4
#define NPX  4096
#define NSZ  24
#define PS   64
#define VINW 520   // ch map: 0-255 ictx, 256-511 pf, 512-514 blended, 515-519 pad
#define HW   34    // half-row LDS width: 32 cols + 2-col halo

// out element offsets
#define OFF0 0        // ref_novel_view (3,4096)
#define OFF1 12288    // blended_img    (3,4096)
#define OFF2 24576    // interp_view    (4,3,4096)
#define OFF3 73728    // weight         (4,4096,24)
#define OFF4 466944   // confs          (4,4096)

// ---------------------------------------------------------------------------
// Static device-global scratch.
// ---------------------------------------------------------------------------
__device__ unsigned g_cc [NS * NPX * 64];   // [s][p][ch]: lo=ce, hi=ctx (bf16)
__device__ float2 g_fld[NS * NPX];          // per-pixel (Aw, Ac) score fields
__device__ unsigned short g_vin [NPX * VINW];  // bf16, 16B-aligned lane groups
__device__ float g_iv  [NS * NPX * 3];    // [s][p][c]
__device__ float g_clg [NS * NPX];        // confNet logit per (source,pixel)
// transposed weights (lane-coalesced on the fast index)
__device__ float g_fwT [162 * 64];        // [(ic*9+t)][oc]
__device__ float g_cwT [27 * 64];         // [(ic*9+t)][oc]
__device__ float g_pwT [54 * 64];         // [(ic*9+t)][oc]
__device__ unsigned short g_vwT [3 * 9 * VINW];  // bf16 [(oc*9+t)][nch], remapped

__device__ __forceinline__ int clampi(int v, int lo, int hi) {
    return v < lo ? lo : (v > hi ? hi : v);
}
__device__ __forceinline__ unsigned bf16_bits(float f) {   // RNE f32->bf16 bits
    unsigned u = __float_as_uint(f);
    return (u + 0x7fffu + ((u >> 16) & 1u)) >> 16;
}
__device__ __forceinline__ float bf16_lo(unsigned v) { return __uint_as_float(v << 16); }
__device__ __forceinline__ float bf16_hi(unsigned v) { return __uint_as_float(v & 0xffff0000u); }
__device__ __forceinline__ float ldbf(const unsigned short* p, int i) {
    return __uint_as_float(((unsigned)p[i]) << 16);
}

// ---------------------------------------------------------------------------
// Kernel 0: weight transposes (same work every call).
// ---------------------------------------------------------------------------
__global__ void k_prep(const float* __restrict__ fw, const float* __restrict__ cw,
                       const float* __restrict__ pw, const float* __restrict__ vw)
{
    const int i = blockIdx.x * 256 + threadIdx.x;
    const int stride = gridDim.x * 256;
    for (int d = i; d < 162 * 64; d += stride) g_fwT[d] = fw[(d & 63) * 162 + (d >> 6)];
    for (int d = i; d < 27 * 64;  d += stride) g_cwT[d] = cw[(d & 63) * 27  + (d >> 6)];
    for (int d = i; d < 54 * 64;  d += stride) g_pwT[d] = pw[(d & 63) * 54  + (d >> 6)];
    for (int d = i; d < 3 * 9 * VINW; d += stride) {
        const int oc = d / (9 * VINW), rem = d % (9 * VINW);
        const int t = rem / VINW, nch = rem % VINW;
        float v = 0.f;
        if (nch < 256)      v = vw[(oc * 515 + 3 + nch) * 9 + t];
        else if (nch < 512) v = vw[(oc * 515 + 259 + (nch - 256)) * 9 + t];
        else if (nch < 515) v = vw[(oc * 515 + (nch - 512)) * 9 + t];
        g_vwT[d] = (unsigned short)bf16_bits(v);
    }
}

// ---------------------------------------------------------------------------
// Kernel 1: flowRefNet + ctxNet convs, HALF-ROW-TILED (2 blocks/CU).
// block = (s, py, half): 256 threads = 4 waves; wave w -> 8 px, lane = oc.
// ---------------------------------------------------------------------------
__global__ __launch_bounds__(256) void k_convs(
    const float* __restrict__ sv, const float* __restrict__ sf, const float* __restrict__ wv,
    const float* __restrict__ flow_b, const float* __restrict__ ctx_b,
    const float* __restrict__ wnet_w, const float* __restrict__ cnet_w)
{
    __shared__ float lds[18 * 3 * HW];
    const int blk = blockIdx.x;
    const int s = blk >> 7, py = (blk & 127) >> 1, half = blk & 1;
    const int tid = threadIdx.x;

    for (int i = tid; i < 18 * 3 * HW; i += 256) {
        const int lc = i % HW;
        const int rr = (i / HW) % 3;
        const int pl = i / (3 * HW);
        const int iy = py + rr - 1;
        const int ix = half * 32 + lc - 1;
        float v = 0.f;
        if ((unsigned)iy < 64u && (unsigned)ix < 64u) {
            const float* src = (pl < 6) ? (sf + (s * 6 + pl) * NPX)
                             : (pl < 9) ? (sv + (s * 3 + (pl - 6)) * NPX)
                                        : (wv + (s * 9 + (pl - 9)) * NPX);
            v = src[iy * 64 + ix];
        }
        lds[i] = v;
    }
    __syncthreads();

    const int oc  = tid & 63;
    const int wid = tid >> 6;
    const int lc0 = wid * 8;                 // local window base (global col - 1)

    float acc_ce[8], acc_ctx[8];
    const float fb = flow_b[oc], cb = ctx_b[oc];
    #pragma unroll
    for (int j = 0; j < 8; ++j) { acc_ce[j] = fb; acc_ctx[j] = cb; }

    for (int pl = 0; pl < 18; ++pl) {
        float w[9];
        #pragma unroll
        for (int t = 0; t < 9; ++t) w[t] = g_fwT[(pl * 9 + t) * 64 + oc];
        float wc[9];
        const bool has_ctx = (pl >= 6 && pl < 9);
        if (has_ctx) {
            #pragma unroll
            for (int t = 0; t < 9; ++t) wc[t] = g_cwT[((pl - 6) * 9 + t) * 64 + oc];
        }
        float c0[3], c1[3], c2[3];
        #pragma unroll
        for (int r = 0; r < 3; ++r) {
            c0[r] = lds[(pl * 3 + r) * HW + lc0];
            c1[r] = lds[(pl * 3 + r) * HW + lc0 + 1];
        }
        #pragma unroll
        for (int j = 0; j < 8; ++j) {
            #pragma unroll
            for (int r = 0; r < 3; ++r)
                c2[r] = lds[(pl * 3 + r) * HW + lc0 + j + 2];
            float a = 0.f;
            #pragma unroll
            for (int r = 0; r < 3; ++r)
                a += c0[r] * w[r * 3 + 0] + c1[r] * w[r * 3 + 1] + c2[r] * w[r * 3 + 2];
            acc_ce[j] += a;
            if (has_ctx) {
                float b2 = 0.f;
                #pragma unroll
                for (int r = 0; r < 3; ++r)
                    b2 += c0[r] * wc[r * 3 + 0] + c1[r] * wc[r * 3 + 1] + c2[r] * wc[r * 3 + 2];
                acc_ctx[j] += b2;
            }
            #pragma unroll
            for (int r = 0; r < 3; ++r) { c0[r] = c1[r]; c1[r] = c2[r]; }
        }
    }

    // relu + packed store + per-pixel score fields (Aw/Ac)
    const float Wce = wnet_w[6 + oc], Cce = cnet_w[6 + oc];
    float awsel = 0.f, acsel = 0.f;
    #pragma unroll
    for (int j = 0; j < 8; ++j) {
        const float ce = fmaxf(acc_ce[j], 0.f);
        const float cx = fmaxf(acc_ctx[j], 0.f);
        const int p = py * 64 + half * 32 + wid * 8 + j;
        g_cc[(s * NPX + p) * 64 + oc] = bf16_bits(ce) | (bf16_bits(cx) << 16);
        float gw = ce * Wce, gc = ce * Cce;
        #pragma unroll
        for (int off = 32; off; off >>= 1) {
            gw += __shfl_xor(gw, off, 64);
            gc += __shfl_xor(gc, off, 64);
        }
        awsel = (oc == j) ? gw : awsel;
        acsel = (oc == j) ? gc : acsel;
    }
    if (oc < 8) {
        const int lpx = wid * 8 + oc;        // local px within half-row
        float fwv = 0.f, fcv = 0.f;
        #pragma unroll
        for (int c = 0; c < 6; ++c) {
            const float v = lds[(c * 3 + 1) * HW + lpx + 1];   // center row, sf ch c
            fwv += v * wnet_w[c];
            fcv += v * cnet_w[c];
        }
        g_fld[s * NPX + py * 64 + half * 32 + lpx] = make_float2(awsel + fwv, acsel + fcv);
    }
}

// ---------------------------------------------------------------------------
// Kernel 2: epipolar softmax + interpolations, FIELD-BASED, packed gathers.
// ---------------------------------------------------------------------------
__global__ __launch_bounds__(256) void k_epi(
    const float* __restrict__ sv, const int* __restrict__ nxy,
    const float* __restrict__ spa, const float* __restrict__ ang,
    const float* __restrict__ wnet_w, const float* __restrict__ wnet_b,
    const float* __restrict__ cnet_w,
    float* __restrict__ out)
{
    const int blk = blockIdx.x;
    const int wid = threadIdx.x >> 6;
    const int l   = threadIdx.x & 63;
    const int s   = (blk & 7) >> 1;                       // XCD-pair swizzle
    const int p   = (blk >> 3) * 8 + (blk & 1) * 4 + wid;

    int q[NSZ];
    #pragma unroll
    for (int e = 0; e < 8; ++e) {
        int nx = nxy[((s * NPX + p) * 8 + e) * 2 + 0];
        int ny = nxy[((s * NPX + p) * 8 + e) * 2 + 1];
        nx = clampi(nx, 0, 63);
        #pragma unroll
        for (int k = 0; k < 3; ++k) {
            int y = clampi(ny + k - 1, 0, 63);
            q[e * 3 + k] = y * 64 + nx;
        }
    }

    const unsigned* ccp = g_cc + (size_t)s * NPX * 64;
    unsigned cc[NSZ];
    #pragma unroll
    for (int n = 0; n < NSZ; ++n) cc[n] = ccp[q[n] * 64 + l];

    // lane = channel: mu/var -> base scalars (2-scalar allreduce)
    float mu = 0.f;
    #pragma unroll
    for (int n = 0; n < NSZ; ++n) mu += bf16_lo(cc[n]);
    mu *= (1.f / 24.f);
    float var = 0.f;
    #pragma unroll
    for (int n = 0; n < NSZ; ++n) { const float d = bf16_lo(cc[n]) - mu; var += d * d; }
    var *= (1.f / 23.f);   // ddof=1

    float pw = mu * wnet_w[70 + l] + var * wnet_w[134 + l];
    float pc = mu * cnet_w[70 + l] + var * cnet_w[134 + l];
    #pragma unroll
    for (int off = 32; off; off >>= 1) {
        pw += __shfl_xor(pw, off, 64);
        pc += __shfl_xor(pc, off, 64);
    }
    const float base_w = pw, base_c = pc;

    // lane = band element: field gather + spa/ang terms -> logit
    float Aw = 0.f, Ac = 0.f;
    if (l < NSZ) {
        const float2 A = g_fld[s * NPX + q[l]];
        Aw = A.x; Ac = A.y;
        #pragma unroll
        for (int c = 0; c < 2; ++c) {
            const float v = spa[((s * 2 + c) * NSZ + l) * NPX + p];
            Aw += v * wnet_w[198 + c];
            Ac += v * cnet_w[198 + c];
        }
        #pragma unroll
        for (int c = 0; c < 6; ++c) {
            const float v = ang[((s * 6 + c) * NSZ + l) * NPX + p];
            Aw += v * wnet_w[200 + c];
            Ac += v * cnet_w[200 + c];
        }
    }

    // softmax over the 24 active lanes
    float logit = (l < NSZ) ? (Aw + base_w + wnet_b[0]) : -1e30f;
    float mx = logit;
    #pragma unroll
    for (int off = 32; off; off >>= 1) mx = fmaxf(mx, __shfl_xor(mx, off, 64));
    float e = (l < NSZ) ? __expf(logit - mx) : 0.f;
    float ssum = e;
    #pragma unroll
    for (int off = 32; off; off >>= 1) ssum += __shfl_xor(ssum, off, 64);
    const float wgt = e / ssum;

    // confNet logit (Σwgt = 1 makes the base additive)
    float clp = (l < NSZ) ? (Ac + base_c) * wgt : 0.f;
    #pragma unroll
    for (int off = 32; off; off >>= 1) clp += __shfl_xor(clp, off, 64);
    if (l == 0) g_clg[s * NPX + p] = clp;

    // out3: weight [s][p][n]
    if (l < NSZ) out[OFF3 + (s * NPX + p) * NSZ + l] = wgt;

    // broadcast all 24 weights
    float wall[NSZ];
    #pragma unroll
    for (int n = 0; n < NSZ; ++n) wall[n] = __shfl(wgt, n, 64);

    // interp_ctx channel l (hi halves of the same gathered dwords)
    float sc = 0.f;
    #pragma unroll
    for (int n = 0; n < NSZ; ++n) sc += bf16_hi(cc[n]) * wall[n];
    g_vin[p * VINW + s * 64 + l] = (unsigned short)bf16_bits(sc);   // ictx base 0

    // interp_view (lanes 0..2)
    if (l < 3) {
        float svv = 0.f;
        #pragma unroll
        for (int n = 0; n < NSZ; ++n) svv += sv[(s * 3 + l) * NPX + q[n]] * wall[n];
        g_iv[(s * NPX + p) * 3 + l] = svv;
        out[OFF2 + (s * 3 + l) * NPX + p] = svv;
    }
}

// ---------------------------------------------------------------------------
// Kernel 3: psvNet + FUSED confNet/blend, HALF-ROW-TILED.
// block = (s, py, half). Blended computed in-block for the 3x34 halo region
// from g_clg/g_iv; s==0 blocks write out1/out4/g_vin blended.
// Planes 0..23 = psv (ic*8+d), 24..26 = blended ic.
// ---------------------------------------------------------------------------
__global__ __launch_bounds__(256) void k_psv(
    const float* __restrict__ psvs, const float* __restrict__ psv_b,
    const float* __restrict__ cnet_b, float* __restrict__ out)
{
    __shared__ float lds[27 * 3 * HW];
    const int blk = blockIdx.x;
    const int s = blk >> 7, py = (blk & 127) >> 1, half = blk & 1;
    const int tid = threadIdx.x;

    for (int i = tid; i < 27 * 3 * HW; i += 256) {
        const int lc = i % HW;
        const int rr = (i / HW) % 3;
        const int pl = i / (3 * HW);
        float v = 0.f;
        if (pl < 24) {
            const int iy = py + rr - 1;
            const int ix = half * 32 + lc - 1;
            if ((unsigned)iy < 64u && (unsigned)ix < 64u)
                v = psvs[(s * 24 + pl) * NPX + iy * 64 + ix];
        }
        lds[i] = v;
    }
    __syncthreads();

    // blended for the halo region (planes 24..26); fused confNet outputs on s==0
    if (tid < 3 * HW) {
        const int r = tid / HW, lc = tid % HW;
        const int iy = py + r - 1, ix = half * 32 + lc - 1;
        if ((unsigned)iy < 64u && (unsigned)ix < 64u) {
            const int p = iy * 64 + ix;
            const float cb = cnet_b[0];
            float lg[NS];
            #pragma unroll
            for (int ss = 0; ss < NS; ++ss) lg[ss] = g_clg[ss * NPX + p] + cb;
            float m = lg[0];
            #pragma unroll
            for (int ss = 1; ss < NS; ++ss) m = fmaxf(m, lg[ss]);
            float ssum = 0.f;
            float conf[NS];
            #pragma unroll
            for (int ss = 0; ss < NS; ++ss) { conf[ss] = __expf(lg[ss] - m); ssum += conf[ss]; }
            const float inv = 1.f / ssum;
            #pragma unroll
            for (int ss = 0; ss < NS; ++ss) conf[ss] *= inv;
            float bl[3];
            #pragma unroll
            for (int c = 0; c < 3; ++c) {
                float a = 0.f;
                #pragma unroll
                for (int ss = 0; ss < NS; ++ss)
                    a += g_iv[(ss * NPX + p) * 3 + c] * conf[ss];
                bl[c] = a;
                lds[((24 + c) * 3 + r) * HW + lc] = a;
            }
            if (s == 0 && r == 1 && lc >= 1 && lc <= 32) {
                #pragma unroll
                for (int ss = 0; ss < NS; ++ss) out[OFF4 + ss * NPX + p] = conf[ss];
                #pragma unroll
                for (int c = 0; c < 3; ++c) {
                    out[OFF1 + c * NPX + p] = bl[c];
                    g_vin[p * VINW + 512 + c] = (unsigned short)bf16_bits(bl[c]);
                }
            }
        }
    }
    __syncthreads();

    const int oc  = tid & 63;
    const int wid = tid >> 6;
    const int lc0 = wid * 8;
    const float bias = psv_b[oc];

    float wp[3][9];
    #pragma unroll
    for (int ic = 0; ic < 3; ++ic)
        #pragma unroll
        for (int t = 0; t < 9; ++t) wp[ic][t] = g_pwT[(ic * 9 + t) * 64 + oc];

    float bconst[8];
    #pragma unroll
    for (int j = 0; j < 8; ++j) bconst[j] = bias;
    for (int ic = 0; ic < 3; ++ic) {
        float w[9];
        #pragma unroll
        for (int t = 0; t < 9; ++t) w[t] = g_pwT[((3 + ic) * 9 + t) * 64 + oc];
        const int pl = 24 + ic;
        float c0[3], c1[3], c2[3];
        #pragma unroll
        for (int r = 0; r < 3; ++r) {
            c0[r] = lds[(pl * 3 + r) * HW + lc0];
            c1[r] = lds[(pl * 3 + r) * HW + lc0 + 1];
        }
        #pragma unroll
        for (int j = 0; j < 8; ++j) {
            #pragma unroll
            for (int r = 0; r < 3; ++r)
                c2[r] = lds[(pl * 3 + r) * HW + lc0 + j + 2];
            float a = 0.f;
            #pragma unroll
            for (int r = 0; r < 3; ++r)
                a += c0[r] * w[r * 3 + 0] + c1[r] * w[r * 3 + 1] + c2[r] * w[r * 3 + 2];
            bconst[j] += a;
            #pragma unroll
            for (int r = 0; r < 3; ++r) { c0[r] = c1[r]; c1[r] = c2[r]; }
        }
    }

    float acc[8];
    #pragma unroll
    for (int j = 0; j < 8; ++j) acc[j] = 0.f;

    for (int d = 0; d < 8; ++d) {
        float a[8];
        #pragma unroll
        for (int j = 0; j < 8; ++j) a[j] = bconst[j];
        #pragma unroll
        for (int ic = 0; ic < 3; ++ic) {
            const int pl = ic * 8 + d;
            float c0[3], c1[3], c2[3];
            #pragma unroll
            for (int r = 0; r < 3; ++r) {
                c0[r] = lds[(pl * 3 + r) * HW + lc0];
                c1[r] = lds[(pl * 3 + r) * HW + lc0 + 1];
            }
            #pragma unroll
            for (int j = 0; j < 8; ++j) {
                #pragma unroll
                for (int r = 0; r < 3; ++r)
                    c2[r] = lds[(pl * 3 + r) * HW + lc0 + j + 2];
                float t2 = 0.f;
                #pragma unroll
                for (int r = 0; r < 3; ++r)
                    t2 += c0[r] * wp[ic][r * 3 + 0] + c1[r] * wp[ic][r * 3 + 1] + c2[r] * wp[ic][r * 3 + 2];
                a[j] += t2;
                #pragma unroll
                for (int r = 0; r < 3; ++r) { c0[r] = c1[r]; c1[r] = c2[r]; }
            }
        }
        #pragma unroll
        for (int j = 0; j < 8; ++j) acc[j] += fmaxf(a[j], 0.f);
    }
    #pragma unroll
    for (int j = 0; j < 8; ++j)
        g_vin[(py * 64 + half * 32 + wid * 8 + j) * VINW + 256 + s * 64 + oc] =  // pf base 256
            (unsigned short)bf16_bits(acc[j] * 0.125f);
}

// ---------------------------------------------------------------------------
// Kernel 4: vref conv3x3 over 515 channels -> 3, VECTORIZED (uint4 = 8 bf16).
// ---------------------------------------------------------------------------
__global__ __launch_bounds__(64) void k_vref(
    const float* __restrict__ vref_b, float* __restrict__ out)
{
    const int p = blockIdx.x;
    const int py = p >> 6, px = p & 63;
    const int l = threadIdx.x;

    float acc[3] = {0.f, 0.f, 0.f};
    #pragma unroll
    for (int t = 0; t < 9; ++t) {
        const int iy = py + t / 3 - 1, ix = px + t % 3 - 1;
        if ((unsigned)iy >= 64u || (unsigned)ix >= 64u) continue;
        const int rowbase = (iy * 64 + ix) * VINW;
        const uint4 vv = *(const uint4*)(g_vin + rowbase + 8 * l);
        float v[8];
        v[0] = bf16_lo(vv.x); v[1] = bf16_hi(vv.x);
        v[2] = bf16_lo(vv.y); v[3] = bf16_hi(vv.y);
        v[4] = bf16_lo(vv.z); v[5] = bf16_hi(vv.z);
        v[6] = bf16_lo(vv.w); v[7] = bf16_hi(vv.w);
        #pragma unroll
        for (int oc = 0; oc < 3; ++oc) {
            const uint4 ww = *(const uint4*)(g_vwT + (oc * 9 + t) * VINW + 8 * l);
            acc[oc] += v[0] * bf16_lo(ww.x) + v[1] * bf16_hi(ww.x)
                     + v[2] * bf16_lo(ww.y) + v[3] * bf16_hi(ww.y)
                     + v[4] * bf16_lo(ww.z) + v[5] * bf16_hi(ww.z)
                     + v[6] * bf16_lo(ww.w) + v[7] * bf16_hi(ww.w);
        }
        if (l < 3) {   // blended channels 512-514
            const float bv = ldbf(g_vin, rowbase + 512 + l);
            #pragma unroll
            for (int oc = 0; oc < 3; ++oc)
                acc[oc] += bv * ldbf(g_vwT, (oc * 9 + t) * VINW + 512 + l);
        }
    }
    #pragma unroll
    for (int off = 32; off; off >>= 1) {
        #pragma unroll
        for (int oc = 0; oc < 3; ++oc)
            acc[oc] += __shfl_xor(acc[oc], off, 64);
    }
    if (l == 0) {
        #pragma unroll
        for (int oc = 0; oc < 3; ++oc)
            out[OFF0 + oc * NPX + p] = acc[oc] + vref_b[oc];
    }
}

// ---------------------------------------------------------------------------
extern "C" void kernel_launch(void* const* d_in, const int* in_sizes, int n_in,
                              void* d_out, int out_size, void* d_ws, size_t ws_size,
                              hipStream_t stream)
{
    auto find1 = [&](int sz, int fb) -> int {
        for (int i = 0; i < n_in; ++i) if (in_sizes[i] == sz) return i;
        return fb;
    };
    const int i_sv  = find1(49152, 0);
    const int i_sf  = find1(98304, 1);
    const int i_psv = find1(393216, 2);
    const int i_wv  = find1(147456, 3);
    const int i_nxy = find1(262144, 5);
    const int i_spa = find1(786432, 6);
    const int i_ang = find1(2359296, 7);
    const int i_fw  = find1(10368, 9);
    const int i_cw  = find1(1728, 11);
    const int i_pw  = find1(3456, 17);
    const int i_vw  = find1(13905, 19);
    const int i_vb  = find1(3, 20);
    int i_ww = -1, i_cnw = -1;
    for (int i = 0; i < n_in; ++i)
        if (in_sizes[i] == 206) { if (i_ww < 0) i_ww = i; else { i_cnw = i; break; } }
    if (i_ww  < 0) i_ww  = 13;
    if (i_cnw < 0) i_cnw = 15;
    int b64[3] = {10, 12, 18}; int c64 = 0;
    for (int i = 0; i < n_in && c64 < 3; ++i) if (in_sizes[i] == 64) b64[c64++] = i;
    const int i_fb = b64[0], i_cb = b64[1], i_pb = b64[2];
    int i_wb = -1, i_cnb = -1;
    for (int i = i_fw + 1; i < n_in; ++i)
        if (in_sizes[i] == 1) { if (i_wb < 0) i_wb = i; else { i_cnb = i; break; } }
    if (i_wb  < 0) i_wb  = 14;
    if (i_cnb < 0) i_cnb = 16;

    const float* sv     = (const float*)d_in[i_sv];
    const float* sf     = (const float*)d_in[i_sf];
    const float* psvs   = (const float*)d_in[i_psv];
    const float* wv     = (const float*)d_in[i_wv];
    const int*   nxy    = (const int*)d_in[i_nxy];
    const float* spa    = (const float*)d_in[i_spa];
    const float* ang    = (const float*)d_in[i_ang];
    const float* flow_w = (const float*)d_in[i_fw];
    const float* flow_b = (const float*)d_in[i_fb];
    const float* ctx_w  = (const float*)d_in[i_cw];
    const float* ctx_b  = (const float*)d_in[i_cb];
    const float* wnet_w = (const float*)d_in[i_ww];
    const float* wnet_b = (const float*)d_in[i_wb];
    const float* cnet_w = (const float*)d_in[i_cnw];
    const float* cnet_b = (const float*)d_in[i_cnb];
    const float* psv_w  = (const float*)d_in[i_pw];
    const float* psv_b  = (const float*)d_in[i_pb];
    const float* vref_w = (const float*)d_in[i_vw];
    const float* vref_b = (const float*)d_in[i_vb];
    (void)d_ws; (void)ws_size; (void)out_size;

    float* out = (float*)d_out;

    k_prep <<<64, 256, 0, stream>>>(flow_w, ctx_w, psv_w, vref_w);
    k_convs<<<512, 256, 0, stream>>>(sv, sf, wv, flow_b, ctx_b, wnet_w, cnet_w);
    k_epi  <<<4096, 256, 0, stream>>>(sv, nxy, spa, ang, wnet_w, wnet_b, cnet_w, out);
    k_psv  <<<512, 256, 0, stream>>>(psvs, psv_b, cnet_b, out);
    k_vref <<<4096, 64, 0, stream>>>(vref_b, out);
}